// Round 7
// baseline (197.451 us; speedup 1.0000x reference)
//
#include <hip/hip_runtime.h>

// ---------------- problem constants ----------------
// B*P=32, N=512, D=128, H=4, DK=32, T=3 (tm {0,1,3}; tsel(t)=t+(t>>1))
// Inputs f32, OUTPUT f32.
// R13: 171.5us; k_attn2 57us. R14/R17/R19: S^T orientation retired for good
//   (clean R19 run: 77us; b64 P-store 4-way bank serialization + 16-line tm
//   dwordx4 gathers sit on the critical path; VALU savings real but smaller).
// R15: 170.4us; non-attn kernel STRUCTURE doesn't move total.
// R16: 165.4us BEST; k_attn4 51.4us (tm depth-1 prefetch, VGPR 56).
// R18: kf prefetch + ceil-fma neutral/worse (occ 31->20% costs ~2us only).
// R20: revert to exact R16 k_attn4; single variable = LAUNCH COUNT:
//   XL 4-kernel pipeline collapsed into the proven 3-kernel BIG pipeline
//   (inline-cvt k_qkv_cvt / k_oproj_cvt, no k_prep). Decisive read: total
//   <=158us -> per-launch overhead real; >=164us -> launch count not a lever.

typedef __attribute__((ext_vector_type(8))) short  short8;
typedef __attribute__((ext_vector_type(4))) float  floatx4;

#define WS_BIG   50331648ull                  // q3/k3/v3 (37.7MB) + att (12.6MB)
#define QSCALE   0.25503486f                  // (1/sqrt(32)) * log2(e)

__device__ __forceinline__ unsigned short f2b(float f) {
    union { float f; unsigned int i; } v; v.f = f;
    unsigned int x = v.i;
    return (unsigned short)((x + 0x7fffu + ((x >> 16) & 1u)) >> 16);
}
__device__ __forceinline__ unsigned int fbits(float f) {
    union { float f; unsigned int i; } v; v.f = f; return v.i;
}
__device__ __forceinline__ short8 cvt8(const float* p) {
    floatx4 a = *(const floatx4*)p;
    floatx4 b = *(const floatx4*)(p + 4);
    short8 r;
    r[0] = (short)f2b(a[0]); r[1] = (short)f2b(a[1]);
    r[2] = (short)f2b(a[2]); r[3] = (short)f2b(a[3]);
    r[4] = (short)f2b(b[0]); r[5] = (short)f2b(b[1]);
    r[6] = (short)f2b(b[2]); r[7] = (short)f2b(b[3]);
    return r;
}

// ---------------- K1: QKV projection, inline f32->bf16 conversion -------------
// grid (32 bp, 4 mt, 3 t). Converts X tile and W tiles on the fly (same f2b
// rounding as the retired k_prep path -> bit-identical outputs).
__global__ __launch_bounds__(256) void k_qkv_cvt(
    const float* __restrict__ X,
    const float* __restrict__ Wq, const float* __restrict__ Wk,
    const float* __restrict__ Wv,
    unsigned short* __restrict__ q_ws, unsigned short* __restrict__ k_ws,
    unsigned short* __restrict__ v_ws,
    int wstride, int ostride)
{
    int bp = blockIdx.x, mt = blockIdx.y, tz = blockIdx.z;
    __shared__ unsigned short Xs[128 * 128];
    int tid = threadIdx.x;
    int lane = tid & 63, wv = tid >> 6;
    int l15 = lane & 15, quad = lane >> 4;

    const float* Xbase = X + ((size_t)bp * 512 + mt * 128) * 128;
    for (int i = 0; i < 8; ++i) {
        int e = (i * 256 + tid) * 8;
        *(short8*)&Xs[e] = cvt8(&Xbase[e]);
    }
    __syncthreads();

    size_t woff = (size_t)tz * wstride;
    size_t ooff = (size_t)tz * ostride;
    const float* Wsel[3] = { Wq + woff, Wk + woff, Wv + woff };
    unsigned short* Osel[3] = { q_ws + ooff, k_ws + ooff, v_ws + ooff };

    for (int qkv = 0; qkv < 3; ++qkv) {
        const float* Wt = Wsel[qkv];
        unsigned short* Ob = Osel[qkv] + ((size_t)bp * 512 + mt * 128) * 128;
        float sc = (qkv == 0) ? QSCALE : 1.0f;
        for (int ct = 0; ct < 8; ++ct) {
            short8 bfr[4];
            for (int kk = 0; kk < 4; ++kk)
                bfr[kk] = cvt8(&Wt[(size_t)(ct * 16 + l15) * 128 + kk * 32 + quad * 8]);
            floatx4 acc0 = {0.f, 0.f, 0.f, 0.f};
            floatx4 acc1 = {0.f, 0.f, 0.f, 0.f};
            int rt0 = wv * 2, rt1 = wv * 2 + 1;
            for (int kk = 0; kk < 4; ++kk) {
                short8 a0 = *(const short8*)&Xs[(rt0 * 16 + l15) * 128 + kk * 32 + quad * 8];
                short8 a1 = *(const short8*)&Xs[(rt1 * 16 + l15) * 128 + kk * 32 + quad * 8];
                acc0 = __builtin_amdgcn_mfma_f32_16x16x32_bf16(a0, bfr[kk], acc0, 0, 0, 0);
                acc1 = __builtin_amdgcn_mfma_f32_16x16x32_bf16(a1, bfr[kk], acc1, 0, 0, 0);
            }
            int col = ct * 16 + l15;
            for (int i = 0; i < 4; ++i) {
                Ob[(size_t)(rt0 * 16 + quad * 4 + i) * 128 + col] = f2b(acc0[i] * sc);
                Ob[(size_t)(rt1 * 16 + quad * 4 + i) * 128 + col] = f2b(acc1[i] * sc);
            }
        }
    }
}

// ---------------- K2: dense MFMA attention + depth-1 tm pipeline (R16 exact) --
// grid (nc2=2, bp=32, z=t*4+h) = 768 blocks. Proven 51.4us profile: VGPR 56,
// MfmaUtil ~9, VALUBusy ~38, conflicts 786K. tm loads for body (c,s) issued
// one body earlier into rotating sets tmA/tmB; rolling base tpc (+64/c).
__global__ __launch_bounds__(512) void k_attn4(
    const unsigned short* __restrict__ q_ws,   // bf16, pre-scaled by QSCALE
    const unsigned short* __restrict__ k_ws,
    const unsigned short* __restrict__ v_ws,
    const float* __restrict__ tm,
    unsigned short* __restrict__ att_ws,       // [32][512][384] bf16
    int qkv_stride, int toff0)
{
    int nc2 = blockIdx.x;
    int bp = blockIdx.y;
    int z  = blockIdx.z;
    int t = z >> 2, h = z & 3;
    size_t qoff = (size_t)t * (size_t)qkv_stride;
    const float* tmt = tm + (size_t)(t + (t >> 1)) * 262144;
    int toff = toff0 + t * 128;

    __shared__ unsigned short Vt[32][516];
    __shared__ unsigned short Ps[8][16][72];

    int tid = threadIdx.x, lane = tid & 63, wv = tid >> 6;
    int l15 = lane & 15, quad = lane >> 4;

    {
        const unsigned short* vp = v_ws + qoff + ((size_t)bp * 512 + tid) * 128 + h * 32;
        short8 a = *(const short8*)vp;
        short8 b = *(const short8*)(vp + 8);
        short8 c = *(const short8*)(vp + 16);
        short8 d = *(const short8*)(vp + 24);
        #pragma unroll
        for (int j = 0; j < 8; ++j) {
            Vt[j][tid]      = (unsigned short)a[j];
            Vt[8 + j][tid]  = (unsigned short)b[j];
            Vt[16 + j][tid] = (unsigned short)c[j];
            Vt[24 + j][tid] = (unsigned short)d[j];
        }
    }
    int n0 = nc2 * 256 + wv * 16;              // strip 0; strip 1 at n0+128
    short8 qf[2];
    qf[0] = *(const short8*)&q_ws[qoff +
        ((size_t)bp * 512 + n0 + l15) * 128 + h * 32 + quad * 8];
    qf[1] = *(const short8*)&q_ws[qoff +
        ((size_t)bp * 512 + n0 + 128 + l15) * 128 + h * 32 + quad * 8];
    __syncthreads();

    const unsigned short* Kb = k_ws + qoff + (size_t)bp * 512 * 128 + h * 32;
    // per-lane tm base: row (n0 + s*128 + quad*4 + i), col (mb + ti*16 + l15)
    const float* tpc = tmt + (size_t)(n0 + quad * 4) * 512 + l15;

    floatx4 O0[2] = {{0.f,0.f,0.f,0.f},{0.f,0.f,0.f,0.f}};
    floatx4 O1[2] = {{0.f,0.f,0.f,0.f},{0.f,0.f,0.f,0.f}};
    float za[2][4] = {{0.f,0.f,0.f,0.f},{0.f,0.f,0.f,0.f}};
    const floatx4 zero4 = {0.f, 0.f, 0.f, 0.f};

    float tmA[16], tmB[16];                    // [ti*4+i], rotating sets
    #pragma unroll
    for (int ti = 0; ti < 4; ++ti)
        #pragma unroll
        for (int i = 0; i < 4; ++i)
            tmA[ti * 4 + i] = tpc[i * 512 + ti * 16];   // (c=0, s=0)

    for (int c = 0; c < 8; ++c) {
        int mb = c * 64;
        short8 kf0 = *(const short8*)&Kb[(size_t)(mb +  0 + l15) * 128 + quad * 8];
        short8 kf1 = *(const short8*)&Kb[(size_t)(mb + 16 + l15) * 128 + quad * 8];
        short8 kf2 = *(const short8*)&Kb[(size_t)(mb + 32 + l15) * 128 + quad * 8];
        short8 kf3 = *(const short8*)&Kb[(size_t)(mb + 48 + l15) * 128 + quad * 8];

        // ================= s = 0 : prefetch (c, s=1) into tmB =================
        #pragma unroll
        for (int ti = 0; ti < 4; ++ti)
            #pragma unroll
            for (int i = 0; i < 4; ++i)
                tmB[ti * 4 + i] = tpc[(128 + i) * 512 + ti * 16];
        {
            floatx4 S[4];
            S[0] = __builtin_amdgcn_mfma_f32_16x16x32_bf16(qf[0], kf0, zero4, 0, 0, 0);
            S[1] = __builtin_amdgcn_mfma_f32_16x16x32_bf16(qf[0], kf1, zero4, 0, 0, 0);
            S[2] = __builtin_amdgcn_mfma_f32_16x16x32_bf16(qf[0], kf2, zero4, 0, 0, 0);
            S[3] = __builtin_amdgcn_mfma_f32_16x16x32_bf16(qf[0], kf3, zero4, 0, 0, 0);
            #pragma unroll
            for (int ti = 0; ti < 4; ++ti) {
                #pragma unroll
                for (int i = 0; i < 4; ++i) {
                    float tmv = tmA[ti * 4 + i];
                    float e = __builtin_amdgcn_exp2f(S[ti][i]);
                    za[0][i] += (tmv != 0.0f) ? e : 0.0f;
                    float w = e * tmv;                    // ==0 when masked
                    Ps[wv][quad * 4 + i][ti * 16 + l15] =
                        (unsigned short)((fbits(w) + 0x8000u) >> 16);  // half-up
                }
            }
            #pragma unroll
            for (int kc = 0; kc < 2; ++kc) {
                short8 pa  = *(const short8*)&Ps[wv][l15][kc * 32 + quad * 8];
                short8 vb0 = *(const short8*)&Vt[l15][mb + kc * 32 + quad * 8];
                short8 vb1 = *(const short8*)&Vt[16 + l15][mb + kc * 32 + quad * 8];
                O0[0] = __builtin_amdgcn_mfma_f32_16x16x32_bf16(pa, vb0, O0[0], 0, 0, 0);
                O1[0] = __builtin_amdgcn_mfma_f32_16x16x32_bf16(pa, vb1, O1[0], 0, 0, 0);
            }
        }

        // ================= s = 1 : prefetch (c+1, s=0) into tmA ===============
        #pragma unroll
        for (int ti = 0; ti < 4; ++ti)
            #pragma unroll
            for (int i = 0; i < 4; ++i)
                tmA[ti * 4 + i] = tpc[i * 512 + 64 + ti * 16];
        {
            floatx4 S[4];
            S[0] = __builtin_amdgcn_mfma_f32_16x16x32_bf16(qf[1], kf0, zero4, 0, 0, 0);
            S[1] = __builtin_amdgcn_mfma_f32_16x16x32_bf16(qf[1], kf1, zero4, 0, 0, 0);
            S[2] = __builtin_amdgcn_mfma_f32_16x16x32_bf16(qf[1], kf2, zero4, 0, 0, 0);
            S[3] = __builtin_amdgcn_mfma_f32_16x16x32_bf16(qf[1], kf3, zero4, 0, 0, 0);
            #pragma unroll
            for (int ti = 0; ti < 4; ++ti) {
                #pragma unroll
                for (int i = 0; i < 4; ++i) {
                    float tmv = tmB[ti * 4 + i];
                    float e = __builtin_amdgcn_exp2f(S[ti][i]);
                    za[1][i] += (tmv != 0.0f) ? e : 0.0f;
                    float w = e * tmv;
                    Ps[wv][quad * 4 + i][ti * 16 + l15] =
                        (unsigned short)((fbits(w) + 0x8000u) >> 16);
                }
            }
            #pragma unroll
            for (int kc = 0; kc < 2; ++kc) {
                short8 pa  = *(const short8*)&Ps[wv][l15][kc * 32 + quad * 8];
                short8 vb0 = *(const short8*)&Vt[l15][mb + kc * 32 + quad * 8];
                short8 vb1 = *(const short8*)&Vt[16 + l15][mb + kc * 32 + quad * 8];
                O0[1] = __builtin_amdgcn_mfma_f32_16x16x32_bf16(pa, vb0, O0[1], 0, 0, 0);
                O1[1] = __builtin_amdgcn_mfma_f32_16x16x32_bf16(pa, vb1, O1[1], 0, 0, 0);
            }
        }
        tpc += 64;
    }

    #pragma unroll
    for (int s = 0; s < 2; ++s) {
        #pragma unroll
        for (int d = 1; d < 16; d <<= 1) {
            #pragma unroll
            for (int i = 0; i < 4; ++i) za[s][i] += __shfl_xor(za[s][i], d, 64);
        }
        #pragma unroll
        for (int i = 0; i < 4; ++i) {
            float rz = 1.0f / za[s][i];
            size_t row = (size_t)bp * 512 + n0 + s * 128 + quad * 4 + i;
            att_ws[row * 384 + toff + h * 32 + l15]      = f2b(O0[s][i] * rz);
            att_ws[row * 384 + toff + h * 32 + 16 + l15] = f2b(O1[s][i] * rz);
        }
    }
}

// ---------------- K3: out-projection + residual + LayerNorm, inline cvt -------
__global__ __launch_bounds__(256) void k_oproj_cvt(
    const unsigned short* __restrict__ att_ws,
    const float* __restrict__ Wo,
    const float* __restrict__ X,
    const float* __restrict__ gamma,
    const float* __restrict__ beta,
    float* __restrict__ out)
{
    int bp = blockIdx.x;
    int mt = blockIdx.y;
    __shared__ unsigned short As[64 * 128];
    __shared__ unsigned short Ws[128 * 128];
    int tid = threadIdx.x, lane = tid & 63, wv = tid >> 6;
    int l15 = lane & 15, quad = lane >> 4;

    floatx4 acc[8];
    for (int ct = 0; ct < 8; ++ct) acc[ct] = (floatx4){0.f, 0.f, 0.f, 0.f};
    size_t rowbase = (size_t)bp * 512 + mt * 64;

    for (int kc = 0; kc < 3; ++kc) {
        __syncthreads();
        for (int i = 0; i < 4; ++i) {
            int flat = i * 256 + tid;
            int row = flat >> 4, colg = (flat & 15) * 8;
            *(short8*)&As[row * 128 + colg] =
                *(const short8*)&att_ws[(rowbase + row) * 384 + kc * 128 + colg];
        }
        for (int i = 0; i < 8; ++i) {
            int flat = i * 256 + tid;
            int row = flat >> 4, colg = (flat & 15) * 8;
            *(short8*)&Ws[row * 128 + colg] = cvt8(&Wo[(size_t)row * 384 + kc * 128 + colg]);
        }
        __syncthreads();
        for (int ct = 0; ct < 8; ++ct) {
            for (int kk = 0; kk < 4; ++kk) {
                short8 a = *(const short8*)&As[(wv * 16 + l15) * 128 + kk * 32 + quad * 8];
                short8 b = *(const short8*)&Ws[(ct * 16 + l15) * 128 + kk * 32 + quad * 8];
                acc[ct] = __builtin_amdgcn_mfma_f32_16x16x32_bf16(a, b, acc[ct], 0, 0, 0);
            }
        }
    }

    for (int i = 0; i < 4; ++i) {
        int lrow = wv * 16 + quad * 4 + i;
        size_t grow = rowbase + lrow;
        float vals[8];
        float s = 0.f, sq = 0.f;
        for (int ct = 0; ct < 8; ++ct) {
            int col = ct * 16 + l15;
            float v = acc[ct][i] + X[grow * 128 + col];
            vals[ct] = v;
            s += v; sq += v * v;
        }
        for (int d = 1; d < 16; d <<= 1) {
            s  += __shfl_xor(s, d, 64);
            sq += __shfl_xor(sq, d, 64);
        }
        float mu = s * (1.0f / 128.0f);
        float var = sq * (1.0f / 128.0f) - mu * mu;
        float rs = rsqrtf(var + 1e-5f);
        for (int ct = 0; ct < 8; ++ct) {
            int col = ct * 16 + l15;
            out[grow * 128 + col] = (vals[ct] - mu) * rs * gamma[col] + beta[col];
        }
    }
}

// ---------------- launcher ----------------
extern "C" void kernel_launch(void* const* d_in, const int* in_sizes, int n_in,
                              void* d_out, int out_size, void* d_ws, size_t ws_size,
                              hipStream_t stream) {
    const float* X     = (const float*)d_in[0];
    const float* TM    = (const float*)d_in[2];
    const float* Wq    = (const float*)d_in[3];
    const float* Wk    = (const float*)d_in[4];
    const float* Wv    = (const float*)d_in[5];
    const float* Wo    = (const float*)d_in[6];
    const float* gamma = (const float*)d_in[7];
    const float* beta  = (const float*)d_in[8];
    float* out = (float*)d_out;

    char* ws = (char*)d_ws;
    const size_t QKV1 = 2097152;             // elems per t per tensor
    const size_t QKV1B = QKV1 * 2;           // 4 MB

    if (ws_size >= WS_BIG) {
        // R20: single 3-kernel pipeline for all big-workspace cases (was 4
        // kernels in the XL path; k_prep folded into inline cvt).
        unsigned short* q3  = (unsigned short*)(ws);
        unsigned short* k3  = (unsigned short*)(ws + 3 * QKV1B);
        unsigned short* v3  = (unsigned short*)(ws + 6 * QKV1B);
        unsigned short* att = (unsigned short*)(ws + 9 * QKV1B);
        k_qkv_cvt<<<dim3(32, 4, 3), 256, 0, stream>>>(
            X, Wq, Wk, Wv, q3, k3, v3, 16384, (int)QKV1);
        k_attn4<<<dim3(2, 32, 12), 512, 0, stream>>>(q3, k3, v3, TM, att, (int)QKV1, 0);
        k_oproj_cvt<<<dim3(32, 8), 256, 0, stream>>>(att, Wo, X, gamma, beta, out);
    } else {
        unsigned short* q_ws   = (unsigned short*)(ws);
        unsigned short* k_ws   = (unsigned short*)(ws + QKV1B);
        unsigned short* v_ws   = (unsigned short*)(ws + 2 * QKV1B);
        unsigned short* att_ws = (unsigned short*)(ws + 3 * QKV1B);
        const int tsel[3] = {0, 1, 3};
        for (int t = 0; t < 3; ++t) {
            k_qkv_cvt<<<dim3(32, 4, 1), 256, 0, stream>>>(
                X, Wq + (size_t)t * 16384, Wk + (size_t)t * 16384, Wv + (size_t)t * 16384,
                q_ws, k_ws, v_ws, 0, 0);
            k_attn4<<<dim3(2, 32, 4), 512, 0, stream>>>(
                q_ws, k_ws, v_ws, TM + (size_t)tsel[t] * 262144, att_ws, 0, t * 128);
        }
        k_oproj_cvt<<<dim3(32, 8), 256, 0, stream>>>(att_ws, Wo, X, gamma, beta, out);
    }
}

// Round 8
// 190.620 us; speedup vs baseline: 1.0358x; 1.0358x over previous
//
#include <hip/hip_runtime.h>

// ---------------- problem constants ----------------
// B*P=32, N=512, D=128, H=4, DK=32, T=3 (tm {0,1,3}; tsel(t)=t+(t>>1))
// Inputs f32, OUTPUT f32.
// R16: 165.4us BEST. k_attn4 51.4us (tm depth-1 prefetch, VGPR 56).
// R14/R17/R19: S^T orientation retired (77us clean run; P-store bank serial +
//   tm gather shape). R18: kf prefetch/ceil-fma neutral. R15: non-attn kernel
//   STRUCTURE not a lever. R20 FAILED (197.5): confounded test -- swapped in
//   k_qkv_cvt (384 blk, serial qkv loop, scalar stores) which itself runs 55us
//   (MfmaUtil 3.1, occ 12.6, conflicts 8.3M); launch-count question unanswered.
// R21: clean fusion test from PROVEN parts: k_qkv_fused = k_qkv_pre2 structure
//   (1152 blocks, one (qkv,t)/block, LDS-repack short8 stores) + inline cvt8
//   of X/W tiles (bit-identical f2b) -> k_prep launch + 27MB Xb/Wb round-trip
//   eliminated. k_attn4 exact R16. k_oproj_cvt proven. 3 launches.
//   DECISIVE: total <=158 -> keep; >=163 -> residual is fixed overhead,
//   declare roofline next round.

typedef __attribute__((ext_vector_type(8))) short  short8;
typedef __attribute__((ext_vector_type(4))) float  floatx4;

#define WS_BIG   50331648ull                  // q3/k3/v3 (37.7MB) + att (12.6MB)
#define QSCALE   0.25503486f                  // (1/sqrt(32)) * log2(e)

__device__ __forceinline__ unsigned short f2b(float f) {
    union { float f; unsigned int i; } v; v.f = f;
    unsigned int x = v.i;
    return (unsigned short)((x + 0x7fffu + ((x >> 16) & 1u)) >> 16);
}
__device__ __forceinline__ unsigned int fbits(float f) {
    union { float f; unsigned int i; } v; v.f = f; return v.i;
}
__device__ __forceinline__ short8 cvt8(const float* p) {
    floatx4 a = *(const floatx4*)p;
    floatx4 b = *(const floatx4*)(p + 4);
    short8 r;
    r[0] = (short)f2b(a[0]); r[1] = (short)f2b(a[1]);
    r[2] = (short)f2b(a[2]); r[3] = (short)f2b(a[3]);
    r[4] = (short)f2b(b[0]); r[5] = (short)f2b(b[1]);
    r[6] = (short)f2b(b[2]); r[7] = (short)f2b(b[3]);
    return r;
}

// ---------------- K1: QKV projection, fused f32->bf16 cvt (R21) ---------------
// k_qkv_pre2's proven structure: grid (32 bp, 4 mt, 9 z=(qkv,t)) = 1152 blocks,
// LDS-repacked short8 global stores. Only change: X and W tiles are converted
// in-register from f32 (same f2b rounding -> bit-identical outputs to the
// retired k_prep + k_qkv_pre2 path).
__global__ __launch_bounds__(256) void k_qkv_fused(
    const float* __restrict__ X,             // [32][512][128] f32
    const float* __restrict__ Wq,            // [3 t][128][128] f32 each
    const float* __restrict__ Wk,
    const float* __restrict__ Wv,
    unsigned short* __restrict__ q_ws,
    unsigned short* __restrict__ k_ws,
    unsigned short* __restrict__ v_ws)
{
    int bp = blockIdx.x, mt = blockIdx.y, z = blockIdx.z;
    int qkv = z / 3, t = z % 3;
    __shared__ unsigned short Xs[128 * 128];     // 32 KB
    __shared__ unsigned short Cs[4][32 * 128];   // 32 KB (8KB per wave)
    int tid = threadIdx.x;
    int lane = tid & 63, wv = tid >> 6;
    int l15 = lane & 15, quad = lane >> 4;

    const float* Xbase = X + ((size_t)bp * 512 + mt * 128) * 128;
    for (int i = 0; i < 8; ++i) {
        int e = (i * 256 + tid) * 8;
        *(short8*)&Xs[e] = cvt8(&Xbase[e]);
    }
    __syncthreads();

    const float* Wsel[3] = { Wq, Wk, Wv };
    unsigned short* Osel[3] = { q_ws, k_ws, v_ws };
    int rt0 = wv * 2, rt1 = wv * 2 + 1;

    const float* Wt = Wsel[qkv] + (size_t)t * 16384;
    unsigned short* Ob = Osel[qkv] + (size_t)t * 2097152
                       + ((size_t)bp * 512 + mt * 128 + wv * 32) * 128;
    float sc = (qkv == 0) ? QSCALE : 1.0f;

    for (int ct = 0; ct < 8; ++ct) {
        short8 bfr[4];
        for (int kk = 0; kk < 4; ++kk)
            bfr[kk] = cvt8(&Wt[(size_t)(ct * 16 + l15) * 128 + kk * 32 + quad * 8]);
        floatx4 acc0 = {0.f, 0.f, 0.f, 0.f};
        floatx4 acc1 = {0.f, 0.f, 0.f, 0.f};
        for (int kk = 0; kk < 4; ++kk) {
            short8 a0 = *(const short8*)&Xs[(rt0 * 16 + l15) * 128 + kk * 32 + quad * 8];
            short8 a1 = *(const short8*)&Xs[(rt1 * 16 + l15) * 128 + kk * 32 + quad * 8];
            acc0 = __builtin_amdgcn_mfma_f32_16x16x32_bf16(a0, bfr[kk], acc0, 0, 0, 0);
            acc1 = __builtin_amdgcn_mfma_f32_16x16x32_bf16(a1, bfr[kk], acc1, 0, 0, 0);
        }
        #pragma unroll
        for (int i = 0; i < 4; ++i) {
            int row = quad * 4 + i;
            int swz = (row & 7) << 4;
            int col = (ct * 16 + l15) ^ swz;
            Cs[wv][row * 128 + col]        = f2b(acc0[i] * sc);
            Cs[wv][(16 + row) * 128 + col] = f2b(acc1[i] * sc);
        }
    }
    #pragma unroll
    for (int j = 0; j < 8; ++j) {
        int flat = j * 64 + lane;
        int r = flat >> 4;
        int cg = (flat & 15) * 8;
        int cgs = cg ^ ((r & 7) << 4);
        *(short8*)&Ob[(size_t)r * 128 + cg] = *(const short8*)&Cs[wv][r * 128 + cgs];
    }
}

// ---------------- K2: dense MFMA attention + depth-1 tm pipeline (R16 exact) --
// grid (nc2=2, bp=32, z=t*4+h) = 768 blocks. Proven 51.4us profile: VGPR 56,
// MfmaUtil ~9, VALUBusy ~38, conflicts 786K. tm loads for body (c,s) issued
// one body earlier into rotating sets tmA/tmB; rolling base tpc (+64/c).
__global__ __launch_bounds__(512) void k_attn4(
    const unsigned short* __restrict__ q_ws,   // bf16, pre-scaled by QSCALE
    const unsigned short* __restrict__ k_ws,
    const unsigned short* __restrict__ v_ws,
    const float* __restrict__ tm,
    unsigned short* __restrict__ att_ws,       // [32][512][384] bf16
    int qkv_stride, int toff0)
{
    int nc2 = blockIdx.x;
    int bp = blockIdx.y;
    int z  = blockIdx.z;
    int t = z >> 2, h = z & 3;
    size_t qoff = (size_t)t * (size_t)qkv_stride;
    const float* tmt = tm + (size_t)(t + (t >> 1)) * 262144;
    int toff = toff0 + t * 128;

    __shared__ unsigned short Vt[32][516];
    __shared__ unsigned short Ps[8][16][72];

    int tid = threadIdx.x, lane = tid & 63, wv = tid >> 6;
    int l15 = lane & 15, quad = lane >> 4;

    {
        const unsigned short* vp = v_ws + qoff + ((size_t)bp * 512 + tid) * 128 + h * 32;
        short8 a = *(const short8*)vp;
        short8 b = *(const short8*)(vp + 8);
        short8 c = *(const short8*)(vp + 16);
        short8 d = *(const short8*)(vp + 24);
        #pragma unroll
        for (int j = 0; j < 8; ++j) {
            Vt[j][tid]      = (unsigned short)a[j];
            Vt[8 + j][tid]  = (unsigned short)b[j];
            Vt[16 + j][tid] = (unsigned short)c[j];
            Vt[24 + j][tid] = (unsigned short)d[j];
        }
    }
    int n0 = nc2 * 256 + wv * 16;              // strip 0; strip 1 at n0+128
    short8 qf[2];
    qf[0] = *(const short8*)&q_ws[qoff +
        ((size_t)bp * 512 + n0 + l15) * 128 + h * 32 + quad * 8];
    qf[1] = *(const short8*)&q_ws[qoff +
        ((size_t)bp * 512 + n0 + 128 + l15) * 128 + h * 32 + quad * 8];
    __syncthreads();

    const unsigned short* Kb = k_ws + qoff + (size_t)bp * 512 * 128 + h * 32;
    // per-lane tm base: row (n0 + s*128 + quad*4 + i), col (mb + ti*16 + l15)
    const float* tpc = tmt + (size_t)(n0 + quad * 4) * 512 + l15;

    floatx4 O0[2] = {{0.f,0.f,0.f,0.f},{0.f,0.f,0.f,0.f}};
    floatx4 O1[2] = {{0.f,0.f,0.f,0.f},{0.f,0.f,0.f,0.f}};
    float za[2][4] = {{0.f,0.f,0.f,0.f},{0.f,0.f,0.f,0.f}};
    const floatx4 zero4 = {0.f, 0.f, 0.f, 0.f};

    float tmA[16], tmB[16];                    // [ti*4+i], rotating sets
    #pragma unroll
    for (int ti = 0; ti < 4; ++ti)
        #pragma unroll
        for (int i = 0; i < 4; ++i)
            tmA[ti * 4 + i] = tpc[i * 512 + ti * 16];   // (c=0, s=0)

    for (int c = 0; c < 8; ++c) {
        int mb = c * 64;
        short8 kf0 = *(const short8*)&Kb[(size_t)(mb +  0 + l15) * 128 + quad * 8];
        short8 kf1 = *(const short8*)&Kb[(size_t)(mb + 16 + l15) * 128 + quad * 8];
        short8 kf2 = *(const short8*)&Kb[(size_t)(mb + 32 + l15) * 128 + quad * 8];
        short8 kf3 = *(const short8*)&Kb[(size_t)(mb + 48 + l15) * 128 + quad * 8];

        // ================= s = 0 : prefetch (c, s=1) into tmB =================
        #pragma unroll
        for (int ti = 0; ti < 4; ++ti)
            #pragma unroll
            for (int i = 0; i < 4; ++i)
                tmB[ti * 4 + i] = tpc[(128 + i) * 512 + ti * 16];
        {
            floatx4 S[4];
            S[0] = __builtin_amdgcn_mfma_f32_16x16x32_bf16(qf[0], kf0, zero4, 0, 0, 0);
            S[1] = __builtin_amdgcn_mfma_f32_16x16x32_bf16(qf[0], kf1, zero4, 0, 0, 0);
            S[2] = __builtin_amdgcn_mfma_f32_16x16x32_bf16(qf[0], kf2, zero4, 0, 0, 0);
            S[3] = __builtin_amdgcn_mfma_f32_16x16x32_bf16(qf[0], kf3, zero4, 0, 0, 0);
            #pragma unroll
            for (int ti = 0; ti < 4; ++ti) {
                #pragma unroll
                for (int i = 0; i < 4; ++i) {
                    float tmv = tmA[ti * 4 + i];
                    float e = __builtin_amdgcn_exp2f(S[ti][i]);
                    za[0][i] += (tmv != 0.0f) ? e : 0.0f;
                    float w = e * tmv;                    // ==0 when masked
                    Ps[wv][quad * 4 + i][ti * 16 + l15] =
                        (unsigned short)((fbits(w) + 0x8000u) >> 16);  // half-up
                }
            }
            #pragma unroll
            for (int kc = 0; kc < 2; ++kc) {
                short8 pa  = *(const short8*)&Ps[wv][l15][kc * 32 + quad * 8];
                short8 vb0 = *(const short8*)&Vt[l15][mb + kc * 32 + quad * 8];
                short8 vb1 = *(const short8*)&Vt[16 + l15][mb + kc * 32 + quad * 8];
                O0[0] = __builtin_amdgcn_mfma_f32_16x16x32_bf16(pa, vb0, O0[0], 0, 0, 0);
                O1[0] = __builtin_amdgcn_mfma_f32_16x16x32_bf16(pa, vb1, O1[0], 0, 0, 0);
            }
        }

        // ================= s = 1 : prefetch (c+1, s=0) into tmA ===============
        #pragma unroll
        for (int ti = 0; ti < 4; ++ti)
            #pragma unroll
            for (int i = 0; i < 4; ++i)
                tmA[ti * 4 + i] = tpc[i * 512 + 64 + ti * 16];
        {
            floatx4 S[4];
            S[0] = __builtin_amdgcn_mfma_f32_16x16x32_bf16(qf[1], kf0, zero4, 0, 0, 0);
            S[1] = __builtin_amdgcn_mfma_f32_16x16x32_bf16(qf[1], kf1, zero4, 0, 0, 0);
            S[2] = __builtin_amdgcn_mfma_f32_16x16x32_bf16(qf[1], kf2, zero4, 0, 0, 0);
            S[3] = __builtin_amdgcn_mfma_f32_16x16x32_bf16(qf[1], kf3, zero4, 0, 0, 0);
            #pragma unroll
            for (int ti = 0; ti < 4; ++ti) {
                #pragma unroll
                for (int i = 0; i < 4; ++i) {
                    float tmv = tmB[ti * 4 + i];
                    float e = __builtin_amdgcn_exp2f(S[ti][i]);
                    za[1][i] += (tmv != 0.0f) ? e : 0.0f;
                    float w = e * tmv;
                    Ps[wv][quad * 4 + i][ti * 16 + l15] =
                        (unsigned short)((fbits(w) + 0x8000u) >> 16);
                }
            }
            #pragma unroll
            for (int kc = 0; kc < 2; ++kc) {
                short8 pa  = *(const short8*)&Ps[wv][l15][kc * 32 + quad * 8];
                short8 vb0 = *(const short8*)&Vt[l15][mb + kc * 32 + quad * 8];
                short8 vb1 = *(const short8*)&Vt[16 + l15][mb + kc * 32 + quad * 8];
                O0[1] = __builtin_amdgcn_mfma_f32_16x16x32_bf16(pa, vb0, O0[1], 0, 0, 0);
                O1[1] = __builtin_amdgcn_mfma_f32_16x16x32_bf16(pa, vb1, O1[1], 0, 0, 0);
            }
        }
        tpc += 64;
    }

    #pragma unroll
    for (int s = 0; s < 2; ++s) {
        #pragma unroll
        for (int d = 1; d < 16; d <<= 1) {
            #pragma unroll
            for (int i = 0; i < 4; ++i) za[s][i] += __shfl_xor(za[s][i], d, 64);
        }
        #pragma unroll
        for (int i = 0; i < 4; ++i) {
            float rz = 1.0f / za[s][i];
            size_t row = (size_t)bp * 512 + n0 + s * 128 + quad * 4 + i;
            att_ws[row * 384 + toff + h * 32 + l15]      = f2b(O0[s][i] * rz);
            att_ws[row * 384 + toff + h * 32 + 16 + l15] = f2b(O1[s][i] * rz);
        }
    }
}

// ---------------- K3: out-projection + residual + LayerNorm, inline cvt -------
// Proven since R13 (never appeared in top-5 -> <51us; R15 showed oproj
// structure is not a lever).
__global__ __launch_bounds__(256) void k_oproj_cvt(
    const unsigned short* __restrict__ att_ws,
    const float* __restrict__ Wo,
    const float* __restrict__ X,
    const float* __restrict__ gamma,
    const float* __restrict__ beta,
    float* __restrict__ out)
{
    int bp = blockIdx.x;
    int mt = blockIdx.y;
    __shared__ unsigned short As[64 * 128];
    __shared__ unsigned short Ws[128 * 128];
    int tid = threadIdx.x, lane = tid & 63, wv = tid >> 6;
    int l15 = lane & 15, quad = lane >> 4;

    floatx4 acc[8];
    for (int ct = 0; ct < 8; ++ct) acc[ct] = (floatx4){0.f, 0.f, 0.f, 0.f};
    size_t rowbase = (size_t)bp * 512 + mt * 64;

    for (int kc = 0; kc < 3; ++kc) {
        __syncthreads();
        for (int i = 0; i < 4; ++i) {
            int flat = i * 256 + tid;
            int row = flat >> 4, colg = (flat & 15) * 8;
            *(short8*)&As[row * 128 + colg] =
                *(const short8*)&att_ws[(rowbase + row) * 384 + kc * 128 + colg];
        }
        for (int i = 0; i < 8; ++i) {
            int flat = i * 256 + tid;
            int row = flat >> 4, colg = (flat & 15) * 8;
            *(short8*)&Ws[row * 128 + colg] = cvt8(&Wo[(size_t)row * 384 + kc * 128 + colg]);
        }
        __syncthreads();
        for (int ct = 0; ct < 8; ++ct) {
            for (int kk = 0; kk < 4; ++kk) {
                short8 a = *(const short8*)&As[(wv * 16 + l15) * 128 + kk * 32 + quad * 8];
                short8 b = *(const short8*)&Ws[(ct * 16 + l15) * 128 + kk * 32 + quad * 8];
                acc[ct] = __builtin_amdgcn_mfma_f32_16x16x32_bf16(a, b, acc[ct], 0, 0, 0);
            }
        }
    }

    for (int i = 0; i < 4; ++i) {
        int lrow = wv * 16 + quad * 4 + i;
        size_t grow = rowbase + lrow;
        float vals[8];
        float s = 0.f, sq = 0.f;
        for (int ct = 0; ct < 8; ++ct) {
            int col = ct * 16 + l15;
            float v = acc[ct][i] + X[grow * 128 + col];
            vals[ct] = v;
            s += v; sq += v * v;
        }
        for (int d = 1; d < 16; d <<= 1) {
            s  += __shfl_xor(s, d, 64);
            sq += __shfl_xor(sq, d, 64);
        }
        float mu = s * (1.0f / 128.0f);
        float var = sq * (1.0f / 128.0f) - mu * mu;
        float rs = rsqrtf(var + 1e-5f);
        for (int ct = 0; ct < 8; ++ct) {
            int col = ct * 16 + l15;
            out[grow * 128 + col] = (vals[ct] - mu) * rs * gamma[col] + beta[col];
        }
    }
}

// ---------------- K1b: small-ws fallback (unchanged, proven) ------------------
__global__ __launch_bounds__(256) void k_qkv_cvt(
    const float* __restrict__ X,
    const float* __restrict__ Wq, const float* __restrict__ Wk,
    const float* __restrict__ Wv,
    unsigned short* __restrict__ q_ws, unsigned short* __restrict__ k_ws,
    unsigned short* __restrict__ v_ws,
    int wstride, int ostride)
{
    int bp = blockIdx.x, mt = blockIdx.y, tz = blockIdx.z;
    __shared__ unsigned short Xs[128 * 128];
    int tid = threadIdx.x;
    int lane = tid & 63, wv = tid >> 6;
    int l15 = lane & 15, quad = lane >> 4;

    const float* Xbase = X + ((size_t)bp * 512 + mt * 128) * 128;
    for (int i = 0; i < 8; ++i) {
        int e = (i * 256 + tid) * 8;
        *(short8*)&Xs[e] = cvt8(&Xbase[e]);
    }
    __syncthreads();

    size_t woff = (size_t)tz * wstride;
    size_t ooff = (size_t)tz * ostride;
    const float* Wsel[3] = { Wq + woff, Wk + woff, Wv + woff };
    unsigned short* Osel[3] = { q_ws + ooff, k_ws + ooff, v_ws + ooff };

    for (int qkv = 0; qkv < 3; ++qkv) {
        const float* Wt = Wsel[qkv];
        unsigned short* Ob = Osel[qkv] + ((size_t)bp * 512 + mt * 128) * 128;
        float sc = (qkv == 0) ? QSCALE : 1.0f;
        for (int ct = 0; ct < 8; ++ct) {
            short8 bfr[4];
            for (int kk = 0; kk < 4; ++kk)
                bfr[kk] = cvt8(&Wt[(size_t)(ct * 16 + l15) * 128 + kk * 32 + quad * 8]);
            floatx4 acc0 = {0.f, 0.f, 0.f, 0.f};
            floatx4 acc1 = {0.f, 0.f, 0.f, 0.f};
            int rt0 = wv * 2, rt1 = wv * 2 + 1;
            for (int kk = 0; kk < 4; ++kk) {
                short8 a0 = *(const short8*)&Xs[(rt0 * 16 + l15) * 128 + kk * 32 + quad * 8];
                short8 a1 = *(const short8*)&Xs[(rt1 * 16 + l15) * 128 + kk * 32 + quad * 8];
                acc0 = __builtin_amdgcn_mfma_f32_16x16x32_bf16(a0, bfr[kk], acc0, 0, 0, 0);
                acc1 = __builtin_amdgcn_mfma_f32_16x16x32_bf16(a1, bfr[kk], acc1, 0, 0, 0);
            }
            int col = ct * 16 + l15;
            for (int i = 0; i < 4; ++i) {
                Ob[(size_t)(rt0 * 16 + quad * 4 + i) * 128 + col] = f2b(acc0[i] * sc);
                Ob[(size_t)(rt1 * 16 + quad * 4 + i) * 128 + col] = f2b(acc1[i] * sc);
            }
        }
    }
}

// ---------------- launcher ----------------
extern "C" void kernel_launch(void* const* d_in, const int* in_sizes, int n_in,
                              void* d_out, int out_size, void* d_ws, size_t ws_size,
                              hipStream_t stream) {
    const float* X     = (const float*)d_in[0];
    const float* TM    = (const float*)d_in[2];
    const float* Wq    = (const float*)d_in[3];
    const float* Wk    = (const float*)d_in[4];
    const float* Wv    = (const float*)d_in[5];
    const float* Wo    = (const float*)d_in[6];
    const float* gamma = (const float*)d_in[7];
    const float* beta  = (const float*)d_in[8];
    float* out = (float*)d_out;

    char* ws = (char*)d_ws;
    const size_t QKV1 = 2097152;             // elems per t per tensor
    const size_t QKV1B = QKV1 * 2;           // 4 MB

    if (ws_size >= WS_BIG) {
        // R21: 3-kernel pipeline, all proven structures; prep fused into qkv.
        unsigned short* q3  = (unsigned short*)(ws);
        unsigned short* k3  = (unsigned short*)(ws + 3 * QKV1B);
        unsigned short* v3  = (unsigned short*)(ws + 6 * QKV1B);
        unsigned short* att = (unsigned short*)(ws + 9 * QKV1B);
        k_qkv_fused<<<dim3(32, 4, 9), 256, 0, stream>>>(X, Wq, Wk, Wv, q3, k3, v3);
        k_attn4<<<dim3(2, 32, 12), 512, 0, stream>>>(q3, k3, v3, TM, att, (int)QKV1, 0);
        k_oproj_cvt<<<dim3(32, 8), 256, 0, stream>>>(att, Wo, X, gamma, beta, out);
    } else {
        unsigned short* q_ws   = (unsigned short*)(ws);
        unsigned short* k_ws   = (unsigned short*)(ws + QKV1B);
        unsigned short* v_ws   = (unsigned short*)(ws + 2 * QKV1B);
        unsigned short* att_ws = (unsigned short*)(ws + 3 * QKV1B);
        const int tsel[3] = {0, 1, 3};
        for (int t = 0; t < 3; ++t) {
            k_qkv_cvt<<<dim3(32, 4, 1), 256, 0, stream>>>(
                X, Wq + (size_t)t * 16384, Wk + (size_t)t * 16384, Wv + (size_t)t * 16384,
                q_ws, k_ws, v_ws, 0, 0);
            k_attn4<<<dim3(2, 32, 4), 512, 0, stream>>>(
                q_ws, k_ws, v_ws, TM + (size_t)tsel[t] * 262144, att_ws, 0, t * 128);
        }
        k_oproj_cvt<<<dim3(32, 8), 256, 0, stream>>>(att_ws, Wo, X, gamma, beta, out);
    }
}

// Round 9
// 167.313 us; speedup vs baseline: 1.1801x; 1.1393x over previous
//
#include <hip/hip_runtime.h>

// ---------------- problem constants ----------------
// B*P=32, N=512, D=128, H=4, DK=32, T=3 (tm {0,1,3}; tsel(t)=t+(t>>1))
// Inputs f32, OUTPUT f32. XL path (ws >= 54.9MB) confirmed.
// R16: 165.4us BEST (k_prep + k_qkv_pre2 + k_attn4 51.4us + k_oproj_pre2).
// Retired: S^T orientation (R14/R17/R19), kf prefetch / ceil-fma (R18),
//   launch fusion (R20 confounded, R21 clean-negative: fused qkv slower than
//   prep+qkv_pre2; non-attn budget 3x-confirmed immovable).
// R22: k_attn7 = k_attn4 + per-strip Ps buffers (Ps[2][...], +18KB LDS ->
//   2 blocks/CU) + body restructure {QK s0,s1 -> P s0 -> P s1 -> PV s0 ->
//   PV s1}. Removes the shared-Ps serialization: s0 exp chain hides under
//   s1 QK MFMAs, s1 exp hides under s0 PV MFMAs (T15 double-pipeline).
//   tm depth-1 prefetch kept. No launch_bounds min-waves (R17 lesson).
//   GATE: WRITE_SIZE ~12.3MB (no spill); k_attn >= 51us -> revert R16, done.

typedef __attribute__((ext_vector_type(8))) short  short8;
typedef __attribute__((ext_vector_type(4))) float  floatx4;

#define WS_BIG   50331648ull                  // q3/k3/v3 (37.7MB) + att (12.6MB)
#define WS_XL    54919168ull                  // + Xb 4MB + Wb 288KB + Wob 96KB
#define QSCALE   0.25503486f                  // (1/sqrt(32)) * log2(e)

__device__ __forceinline__ unsigned short f2b(float f) {
    union { float f; unsigned int i; } v; v.f = f;
    unsigned int x = v.i;
    return (unsigned short)((x + 0x7fffu + ((x >> 16) & 1u)) >> 16);
}
__device__ __forceinline__ unsigned int fbits(float f) {
    union { float f; unsigned int i; } v; v.f = f; return v.i;
}
__device__ __forceinline__ short8 cvt8(const float* p) {
    floatx4 a = *(const floatx4*)p;
    floatx4 b = *(const floatx4*)(p + 4);
    short8 r;
    r[0] = (short)f2b(a[0]); r[1] = (short)f2b(a[1]);
    r[2] = (short)f2b(a[2]); r[3] = (short)f2b(a[3]);
    r[4] = (short)f2b(b[0]); r[5] = (short)f2b(b[1]);
    r[6] = (short)f2b(b[2]); r[7] = (short)f2b(b[3]);
    return r;
}

// ---------------- K0: one-time f32->bf16 conversion of X, Wq/Wk/Wv, Wo --------
__global__ __launch_bounds__(256) void k_prep(
    const float* __restrict__ X,  const float* __restrict__ Wq,
    const float* __restrict__ Wk, const float* __restrict__ Wv,
    const float* __restrict__ Wo,
    unsigned short* __restrict__ Xb, unsigned short* __restrict__ Wb,
    unsigned short* __restrict__ Wob)
{
    size_t i = ((size_t)blockIdx.x * 256 + threadIdx.x) * 8;
    const float* src; unsigned short* dst; size_t off;
    if      (i < 2097152) { src = X;  dst = Xb;          off = i; }
    else if (i < 2146304) { src = Wq; dst = Wb;          off = i - 2097152; }
    else if (i < 2195456) { src = Wk; dst = Wb + 49152;  off = i - 2146304; }
    else if (i < 2244608) { src = Wv; dst = Wb + 98304;  off = i - 2195456; }
    else                  { src = Wo; dst = Wob;         off = i - 2244608; }
    *(short8*)&dst[off] = cvt8(&src[off]);
}

// ---------------- K1a: QKV projection, one (qkv,t) per block (R15-proven) -----
__global__ __launch_bounds__(256) void k_qkv_pre2(
    const unsigned short* __restrict__ Xb,   // [32][512][128] bf16
    const unsigned short* __restrict__ Wb,   // [3 qkv][3 t][128][128] bf16
    unsigned short* __restrict__ q_ws,
    unsigned short* __restrict__ k_ws,
    unsigned short* __restrict__ v_ws)
{
    int bp = blockIdx.x, mt = blockIdx.y, z = blockIdx.z;
    int qkv = z / 3, t = z % 3;
    __shared__ unsigned short Xs[128 * 128];     // 32 KB
    __shared__ unsigned short Cs[4][32 * 128];   // 32 KB (8KB per wave)
    int tid = threadIdx.x;
    int lane = tid & 63, wv = tid >> 6;
    int l15 = lane & 15, quad = lane >> 4;

    const unsigned short* Xbase = Xb + ((size_t)bp * 512 + mt * 128) * 128;
    for (int i = 0; i < 8; ++i) {
        int e = (i * 256 + tid) * 8;
        *(short8*)&Xs[e] = *(const short8*)&Xbase[e];
    }
    __syncthreads();

    unsigned short* Osel[3] = { q_ws, k_ws, v_ws };
    int rt0 = wv * 2, rt1 = wv * 2 + 1;

    const unsigned short* Wt = Wb + qkv * 49152 + t * 16384;
    unsigned short* Ob = Osel[qkv] + (size_t)t * 2097152
                       + ((size_t)bp * 512 + mt * 128 + wv * 32) * 128;
    float sc = (qkv == 0) ? QSCALE : 1.0f;

    for (int ct = 0; ct < 8; ++ct) {
        short8 bfr[4];
        for (int kk = 0; kk < 4; ++kk)
            bfr[kk] = *(const short8*)&Wt[(size_t)(ct * 16 + l15) * 128 + kk * 32 + quad * 8];
        floatx4 acc0 = {0.f, 0.f, 0.f, 0.f};
        floatx4 acc1 = {0.f, 0.f, 0.f, 0.f};
        for (int kk = 0; kk < 4; ++kk) {
            short8 a0 = *(const short8*)&Xs[(rt0 * 16 + l15) * 128 + kk * 32 + quad * 8];
            short8 a1 = *(const short8*)&Xs[(rt1 * 16 + l15) * 128 + kk * 32 + quad * 8];
            acc0 = __builtin_amdgcn_mfma_f32_16x16x32_bf16(a0, bfr[kk], acc0, 0, 0, 0);
            acc1 = __builtin_amdgcn_mfma_f32_16x16x32_bf16(a1, bfr[kk], acc1, 0, 0, 0);
        }
        #pragma unroll
        for (int i = 0; i < 4; ++i) {
            int row = quad * 4 + i;
            int swz = (row & 7) << 4;
            int col = (ct * 16 + l15) ^ swz;
            Cs[wv][row * 128 + col]        = f2b(acc0[i] * sc);
            Cs[wv][(16 + row) * 128 + col] = f2b(acc1[i] * sc);
        }
    }
    #pragma unroll
    for (int j = 0; j < 8; ++j) {
        int flat = j * 64 + lane;
        int r = flat >> 4;
        int cg = (flat & 15) * 8;
        int cgs = cg ^ ((r & 7) << 4);
        *(short8*)&Ob[(size_t)r * 128 + cg] = *(const short8*)&Cs[wv][r * 128 + cgs];
    }
}

// ---------------- K1b: QKV projection, inline-cvt fallback --------------------
__global__ __launch_bounds__(256) void k_qkv_cvt(
    const float* __restrict__ X,
    const float* __restrict__ Wq, const float* __restrict__ Wk,
    const float* __restrict__ Wv,
    unsigned short* __restrict__ q_ws, unsigned short* __restrict__ k_ws,
    unsigned short* __restrict__ v_ws,
    int wstride, int ostride)
{
    int bp = blockIdx.x, mt = blockIdx.y, tz = blockIdx.z;
    __shared__ unsigned short Xs[128 * 128];
    int tid = threadIdx.x;
    int lane = tid & 63, wv = tid >> 6;
    int l15 = lane & 15, quad = lane >> 4;

    const float* Xbase = X + ((size_t)bp * 512 + mt * 128) * 128;
    for (int i = 0; i < 8; ++i) {
        int e = (i * 256 + tid) * 8;
        *(short8*)&Xs[e] = cvt8(&Xbase[e]);
    }
    __syncthreads();

    size_t woff = (size_t)tz * wstride;
    size_t ooff = (size_t)tz * ostride;
    const float* Wsel[3] = { Wq + woff, Wk + woff, Wv + woff };
    unsigned short* Osel[3] = { q_ws + ooff, k_ws + ooff, v_ws + ooff };

    for (int qkv = 0; qkv < 3; ++qkv) {
        const float* Wt = Wsel[qkv];
        unsigned short* Ob = Osel[qkv] + ((size_t)bp * 512 + mt * 128) * 128;
        float sc = (qkv == 0) ? QSCALE : 1.0f;
        for (int ct = 0; ct < 8; ++ct) {
            short8 bfr[4];
            for (int kk = 0; kk < 4; ++kk)
                bfr[kk] = cvt8(&Wt[(size_t)(ct * 16 + l15) * 128 + kk * 32 + quad * 8]);
            floatx4 acc0 = {0.f, 0.f, 0.f, 0.f};
            floatx4 acc1 = {0.f, 0.f, 0.f, 0.f};
            int rt0 = wv * 2, rt1 = wv * 2 + 1;
            for (int kk = 0; kk < 4; ++kk) {
                short8 a0 = *(const short8*)&Xs[(rt0 * 16 + l15) * 128 + kk * 32 + quad * 8];
                short8 a1 = *(const short8*)&Xs[(rt1 * 16 + l15) * 128 + kk * 32 + quad * 8];
                acc0 = __builtin_amdgcn_mfma_f32_16x16x32_bf16(a0, bfr[kk], acc0, 0, 0, 0);
                acc1 = __builtin_amdgcn_mfma_f32_16x16x32_bf16(a1, bfr[kk], acc1, 0, 0, 0);
            }
            int col = ct * 16 + l15;
            for (int i = 0; i < 4; ++i) {
                Ob[(size_t)(rt0 * 16 + quad * 4 + i) * 128 + col] = f2b(acc0[i] * sc);
                Ob[(size_t)(rt1 * 16 + quad * 4 + i) * 128 + col] = f2b(acc1[i] * sc);
            }
        }
    }
}

// ---------------- K2: attention, dual-strip pipeline w/ split Ps (R22) --------
// grid (nc2=2, bp=32, z=t*4+h) = 768 blocks; LDS 69.9KB -> 2 blocks/CU.
// Per c-body: 8 QK MFMAs (both strips) -> P-loop s0 -> P-loop s1 -> PV s0 ->
// PV s1. Separate Ps[s] buffers remove the write-after-read serialization the
// shared buffer forced; exp chains overlap the other strip's MFMAs.
__global__ __launch_bounds__(512) void k_attn7(
    const unsigned short* __restrict__ q_ws,   // bf16, pre-scaled by QSCALE
    const unsigned short* __restrict__ k_ws,
    const unsigned short* __restrict__ v_ws,
    const float* __restrict__ tm,
    unsigned short* __restrict__ att_ws,       // [32][512][384] bf16
    int qkv_stride, int toff0)
{
    int nc2 = blockIdx.x;
    int bp = blockIdx.y;
    int z  = blockIdx.z;
    int t = z >> 2, h = z & 3;
    size_t qoff = (size_t)t * (size_t)qkv_stride;
    const float* tmt = tm + (size_t)(t + (t >> 1)) * 262144;
    int toff = toff0 + t * 128;

    __shared__ unsigned short Vt[32][516];     // 33.0 KB
    __shared__ unsigned short Ps[2][8][16][72];// 36.9 KB (per-strip buffers)

    int tid = threadIdx.x, lane = tid & 63, wv = tid >> 6;
    int l15 = lane & 15, quad = lane >> 4;

    {
        const unsigned short* vp = v_ws + qoff + ((size_t)bp * 512 + tid) * 128 + h * 32;
        short8 a = *(const short8*)vp;
        short8 b = *(const short8*)(vp + 8);
        short8 c = *(const short8*)(vp + 16);
        short8 d = *(const short8*)(vp + 24);
        #pragma unroll
        for (int j = 0; j < 8; ++j) {
            Vt[j][tid]      = (unsigned short)a[j];
            Vt[8 + j][tid]  = (unsigned short)b[j];
            Vt[16 + j][tid] = (unsigned short)c[j];
            Vt[24 + j][tid] = (unsigned short)d[j];
        }
    }
    int n0 = nc2 * 256 + wv * 16;              // strip 0; strip 1 at n0+128
    short8 qf[2];
    qf[0] = *(const short8*)&q_ws[qoff +
        ((size_t)bp * 512 + n0 + l15) * 128 + h * 32 + quad * 8];
    qf[1] = *(const short8*)&q_ws[qoff +
        ((size_t)bp * 512 + n0 + 128 + l15) * 128 + h * 32 + quad * 8];
    __syncthreads();

    const unsigned short* Kb = k_ws + qoff + (size_t)bp * 512 * 128 + h * 32;
    // per-lane tm base: row (n0 + s*128 + quad*4 + i), col (mb + ti*16 + l15)
    const float* tpc = tmt + (size_t)(n0 + quad * 4) * 512 + l15;

    floatx4 O0[2] = {{0.f,0.f,0.f,0.f},{0.f,0.f,0.f,0.f}};
    floatx4 O1[2] = {{0.f,0.f,0.f,0.f},{0.f,0.f,0.f,0.f}};
    float za[2][4] = {{0.f,0.f,0.f,0.f},{0.f,0.f,0.f,0.f}};
    const floatx4 zero4 = {0.f, 0.f, 0.f, 0.f};

    float tmA[16], tmB[16];                    // [ti*4+i], rotating sets
    #pragma unroll
    for (int ti = 0; ti < 4; ++ti)
        #pragma unroll
        for (int i = 0; i < 4; ++i)
            tmA[ti * 4 + i] = tpc[i * 512 + ti * 16];   // (c=0, s=0)

    for (int c = 0; c < 8; ++c) {
        int mb = c * 64;
        short8 kf0 = *(const short8*)&Kb[(size_t)(mb +  0 + l15) * 128 + quad * 8];
        short8 kf1 = *(const short8*)&Kb[(size_t)(mb + 16 + l15) * 128 + quad * 8];
        short8 kf2 = *(const short8*)&Kb[(size_t)(mb + 32 + l15) * 128 + quad * 8];
        short8 kf3 = *(const short8*)&Kb[(size_t)(mb + 48 + l15) * 128 + quad * 8];

        // prefetch tm for this body's s=1 strip
        #pragma unroll
        for (int ti = 0; ti < 4; ++ti)
            #pragma unroll
            for (int i = 0; i < 4; ++i)
                tmB[ti * 4 + i] = tpc[(128 + i) * 512 + ti * 16];

        // -------- QK for BOTH strips (8 back-to-back MFMAs) --------
        floatx4 S0[4], S1[4];
        S0[0] = __builtin_amdgcn_mfma_f32_16x16x32_bf16(qf[0], kf0, zero4, 0, 0, 0);
        S0[1] = __builtin_amdgcn_mfma_f32_16x16x32_bf16(qf[0], kf1, zero4, 0, 0, 0);
        S0[2] = __builtin_amdgcn_mfma_f32_16x16x32_bf16(qf[0], kf2, zero4, 0, 0, 0);
        S0[3] = __builtin_amdgcn_mfma_f32_16x16x32_bf16(qf[0], kf3, zero4, 0, 0, 0);
        S1[0] = __builtin_amdgcn_mfma_f32_16x16x32_bf16(qf[1], kf0, zero4, 0, 0, 0);
        S1[1] = __builtin_amdgcn_mfma_f32_16x16x32_bf16(qf[1], kf1, zero4, 0, 0, 0);
        S1[2] = __builtin_amdgcn_mfma_f32_16x16x32_bf16(qf[1], kf2, zero4, 0, 0, 0);
        S1[3] = __builtin_amdgcn_mfma_f32_16x16x32_bf16(qf[1], kf3, zero4, 0, 0, 0);

        // -------- P-loop strip 0 (consumes tmA, S0; writes Ps[0]) --------
        #pragma unroll
        for (int ti = 0; ti < 4; ++ti) {
            #pragma unroll
            for (int i = 0; i < 4; ++i) {
                float tmv = tmA[ti * 4 + i];
                float e = __builtin_amdgcn_exp2f(S0[ti][i]);
                za[0][i] += (tmv != 0.0f) ? e : 0.0f;
                float w = e * tmv;                    // ==0 when masked
                Ps[0][wv][quad * 4 + i][ti * 16 + l15] =
                    (unsigned short)((fbits(w) + 0x8000u) >> 16);  // half-up
            }
        }
        // -------- P-loop strip 1 (consumes tmB, S1; writes Ps[1]) --------
        #pragma unroll
        for (int ti = 0; ti < 4; ++ti) {
            #pragma unroll
            for (int i = 0; i < 4; ++i) {
                float tmv = tmB[ti * 4 + i];
                float e = __builtin_amdgcn_exp2f(S1[ti][i]);
                za[1][i] += (tmv != 0.0f) ? e : 0.0f;
                float w = e * tmv;
                Ps[1][wv][quad * 4 + i][ti * 16 + l15] =
                    (unsigned short)((fbits(w) + 0x8000u) >> 16);
            }
        }

        // prefetch tmA for next body's s=0 strip (wrap at c=7 unused-valid)
        #pragma unroll
        for (int ti = 0; ti < 4; ++ti)
            #pragma unroll
            for (int i = 0; i < 4; ++i)
                tmA[ti * 4 + i] = tpc[i * 512 + 64 + ti * 16];

        // -------- PV strip 0 --------
        #pragma unroll
        for (int kc = 0; kc < 2; ++kc) {
            short8 pa  = *(const short8*)&Ps[0][wv][l15][kc * 32 + quad * 8];
            short8 vb0 = *(const short8*)&Vt[l15][mb + kc * 32 + quad * 8];
            short8 vb1 = *(const short8*)&Vt[16 + l15][mb + kc * 32 + quad * 8];
            O0[0] = __builtin_amdgcn_mfma_f32_16x16x32_bf16(pa, vb0, O0[0], 0, 0, 0);
            O1[0] = __builtin_amdgcn_mfma_f32_16x16x32_bf16(pa, vb1, O1[0], 0, 0, 0);
        }
        // -------- PV strip 1 --------
        #pragma unroll
        for (int kc = 0; kc < 2; ++kc) {
            short8 pa  = *(const short8*)&Ps[1][wv][l15][kc * 32 + quad * 8];
            short8 vb0 = *(const short8*)&Vt[l15][mb + kc * 32 + quad * 8];
            short8 vb1 = *(const short8*)&Vt[16 + l15][mb + kc * 32 + quad * 8];
            O0[1] = __builtin_amdgcn_mfma_f32_16x16x32_bf16(pa, vb0, O0[1], 0, 0, 0);
            O1[1] = __builtin_amdgcn_mfma_f32_16x16x32_bf16(pa, vb1, O1[1], 0, 0, 0);
        }
        tpc += 64;
    }

    #pragma unroll
    for (int s = 0; s < 2; ++s) {
        #pragma unroll
        for (int d = 1; d < 16; d <<= 1) {
            #pragma unroll
            for (int i = 0; i < 4; ++i) za[s][i] += __shfl_xor(za[s][i], d, 64);
        }
        #pragma unroll
        for (int i = 0; i < 4; ++i) {
            float rz = 1.0f / za[s][i];
            size_t row = (size_t)bp * 512 + n0 + s * 128 + quad * 4 + i;
            att_ws[row * 384 + toff + h * 32 + l15]      = f2b(O0[s][i] * rz);
            att_ws[row * 384 + toff + h * 32 + 16 + l15] = f2b(O1[s][i] * rz);
        }
    }
}

// ---------------- K3a: out-projection, 32-row blocks + ct-split waves ---------
__global__ __launch_bounds__(256) void k_oproj_pre2(
    const unsigned short* __restrict__ att_ws,   // [32][512][384] bf16
    const unsigned short* __restrict__ Wob,      // [128][384] bf16
    const float* __restrict__ X,
    const float* __restrict__ gamma,
    const float* __restrict__ beta,
    float* __restrict__ out)
{
    int bp = blockIdx.x;
    int mt = blockIdx.y;                         // 16 tiles of 32 rows
    __shared__ unsigned short As[32 * 128];      // 8 KB
    __shared__ unsigned short Ws[128 * 128];     // 32 KB
    __shared__ float Ls_s[2][32];                // per-ct-half row partials
    __shared__ float Ls_q[2][32];
    int tid = threadIdx.x, lane = tid & 63, wv = tid >> 6;
    int l15 = lane & 15, quad = lane >> 4;
    int rtile = wv & 1, chalf = wv >> 1;

    floatx4 acc[4];
    for (int ct = 0; ct < 4; ++ct) acc[ct] = (floatx4){0.f, 0.f, 0.f, 0.f};
    size_t rowbase = (size_t)bp * 512 + mt * 32;

    for (int kc = 0; kc < 3; ++kc) {
        __syncthreads();
        for (int i = 0; i < 2; ++i) {
            int flat = i * 256 + tid;
            int row = flat >> 4, colg = (flat & 15) * 8;
            *(short8*)&As[row * 128 + colg] =
                *(const short8*)&att_ws[(rowbase + row) * 384 + kc * 128 + colg];
        }
        for (int i = 0; i < 8; ++i) {
            int flat = i * 256 + tid;
            int row = flat >> 4, colg = (flat & 15) * 8;
            *(short8*)&Ws[row * 128 + colg] =
                *(const short8*)&Wob[(size_t)row * 384 + kc * 128 + colg];
        }
        __syncthreads();
        for (int ct = 0; ct < 4; ++ct) {
            for (int kk = 0; kk < 4; ++kk) {
                short8 a = *(const short8*)&As[(rtile * 16 + l15) * 128 + kk * 32 + quad * 8];
                short8 b = *(const short8*)&Ws[((chalf * 4 + ct) * 16 + l15) * 128 + kk * 32 + quad * 8];
                acc[ct] = __builtin_amdgcn_mfma_f32_16x16x32_bf16(a, b, acc[ct], 0, 0, 0);
            }
        }
    }

    float vals[4][4];                            // [i][ct], static indexing
    #pragma unroll
    for (int i = 0; i < 4; ++i) {
        int lrow = rtile * 16 + quad * 4 + i;
        size_t grow = rowbase + lrow;
        float s = 0.f, sq = 0.f;
        #pragma unroll
        for (int ct = 0; ct < 4; ++ct) {
            int col = (chalf * 4 + ct) * 16 + l15;
            float v = acc[ct][i] + X[grow * 128 + col];
            vals[i][ct] = v;
            s += v; sq += v * v;
        }
        #pragma unroll
        for (int d = 1; d < 16; d <<= 1) {
            s  += __shfl_xor(s, d, 64);
            sq += __shfl_xor(sq, d, 64);
        }
        if (l15 == 0) { Ls_s[chalf][lrow] = s; Ls_q[chalf][lrow] = sq; }
    }
    __syncthreads();
    #pragma unroll
    for (int i = 0; i < 4; ++i) {
        int lrow = rtile * 16 + quad * 4 + i;
        size_t grow = rowbase + lrow;
        float st  = Ls_s[0][lrow] + Ls_s[1][lrow];
        float sqt = Ls_q[0][lrow] + Ls_q[1][lrow];
        float mu = st * (1.0f / 128.0f);
        float var = sqt * (1.0f / 128.0f) - mu * mu;
        float rs = rsqrtf(var + 1e-5f);
        #pragma unroll
        for (int ct = 0; ct < 4; ++ct) {
            int col = (chalf * 4 + ct) * 16 + l15;
            out[grow * 128 + col] = (vals[i][ct] - mu) * rs * gamma[col] + beta[col];
        }
    }
}

// ---------------- K3b: out-projection, inline-cvt fallback --------------------
__global__ __launch_bounds__(256) void k_oproj_cvt(
    const unsigned short* __restrict__ att_ws,
    const float* __restrict__ Wo,
    const float* __restrict__ X,
    const float* __restrict__ gamma,
    const float* __restrict__ beta,
    float* __restrict__ out)
{
    int bp = blockIdx.x;
    int mt = blockIdx.y;
    __shared__ unsigned short As[64 * 128];
    __shared__ unsigned short Ws[128 * 128];
    int tid = threadIdx.x, lane = tid & 63, wv = tid >> 6;
    int l15 = lane & 15, quad = lane >> 4;

    floatx4 acc[8];
    for (int ct = 0; ct < 8; ++ct) acc[ct] = (floatx4){0.f, 0.f, 0.f, 0.f};
    size_t rowbase = (size_t)bp * 512 + mt * 64;

    for (int kc = 0; kc < 3; ++kc) {
        __syncthreads();
        for (int i = 0; i < 4; ++i) {
            int flat = i * 256 + tid;
            int row = flat >> 4, colg = (flat & 15) * 8;
            *(short8*)&As[row * 128 + colg] =
                *(const short8*)&att_ws[(rowbase + row) * 384 + kc * 128 + colg];
        }
        for (int i = 0; i < 8; ++i) {
            int flat = i * 256 + tid;
            int row = flat >> 4, colg = (flat & 15) * 8;
            *(short8*)&Ws[row * 128 + colg] = cvt8(&Wo[(size_t)row * 384 + kc * 128 + colg]);
        }
        __syncthreads();
        for (int ct = 0; ct < 8; ++ct) {
            for (int kk = 0; kk < 4; ++kk) {
                short8 a = *(const short8*)&As[(wv * 16 + l15) * 128 + kk * 32 + quad * 8];
                short8 b = *(const short8*)&Ws[(ct * 16 + l15) * 128 + kk * 32 + quad * 8];
                acc[ct] = __builtin_amdgcn_mfma_f32_16x16x32_bf16(a, b, acc[ct], 0, 0, 0);
            }
        }
    }

    for (int i = 0; i < 4; ++i) {
        int lrow = wv * 16 + quad * 4 + i;
        size_t grow = rowbase + lrow;
        float vals[8];
        float s = 0.f, sq = 0.f;
        for (int ct = 0; ct < 8; ++ct) {
            int col = ct * 16 + l15;
            float v = acc[ct][i] + X[grow * 128 + col];
            vals[ct] = v;
            s += v; sq += v * v;
        }
        for (int d = 1; d < 16; d <<= 1) {
            s  += __shfl_xor(s, d, 64);
            sq += __shfl_xor(sq, d, 64);
        }
        float mu = s * (1.0f / 128.0f);
        float var = sq * (1.0f / 128.0f) - mu * mu;
        float rs = rsqrtf(var + 1e-5f);
        for (int ct = 0; ct < 8; ++ct) {
            int col = ct * 16 + l15;
            out[grow * 128 + col] = (vals[ct] - mu) * rs * gamma[col] + beta[col];
        }
    }
}

// ---------------- launcher ----------------
extern "C" void kernel_launch(void* const* d_in, const int* in_sizes, int n_in,
                              void* d_out, int out_size, void* d_ws, size_t ws_size,
                              hipStream_t stream) {
    const float* X     = (const float*)d_in[0];
    const float* TM    = (const float*)d_in[2];
    const float* Wq    = (const float*)d_in[3];
    const float* Wk    = (const float*)d_in[4];
    const float* Wv    = (const float*)d_in[5];
    const float* Wo    = (const float*)d_in[6];
    const float* gamma = (const float*)d_in[7];
    const float* beta  = (const float*)d_in[8];
    float* out = (float*)d_out;

    char* ws = (char*)d_ws;
    const size_t QKV1 = 2097152;             // elems per t per tensor
    const size_t QKV1B = QKV1 * 2;           // 4 MB

    if (ws_size >= WS_XL) {
        unsigned short* q3  = (unsigned short*)(ws);
        unsigned short* k3  = (unsigned short*)(ws + 3 * QKV1B);
        unsigned short* v3  = (unsigned short*)(ws + 6 * QKV1B);
        unsigned short* att = (unsigned short*)(ws + 9 * QKV1B);
        unsigned short* Xb  = (unsigned short*)(ws + 50331648ull);
        unsigned short* Wb  = (unsigned short*)(ws + 54525952ull);
        unsigned short* Wob = (unsigned short*)(ws + 54820864ull);
        k_prep<<<dim3(1120), 256, 0, stream>>>(X, Wq, Wk, Wv, Wo, Xb, Wb, Wob);
        k_qkv_pre2<<<dim3(32, 4, 9), 256, 0, stream>>>(Xb, Wb, q3, k3, v3);
        k_attn7<<<dim3(2, 32, 12), 512, 0, stream>>>(q3, k3, v3, TM, att, (int)QKV1, 0);
        k_oproj_pre2<<<dim3(32, 16), 256, 0, stream>>>(att, Wob, X, gamma, beta, out);
    } else if (ws_size >= WS_BIG) {
        unsigned short* q3  = (unsigned short*)(ws);
        unsigned short* k3  = (unsigned short*)(ws + 3 * QKV1B);
        unsigned short* v3  = (unsigned short*)(ws + 6 * QKV1B);
        unsigned short* att = (unsigned short*)(ws + 9 * QKV1B);
        k_qkv_cvt<<<dim3(32, 4, 3), 256, 0, stream>>>(
            X, Wq, Wk, Wv, q3, k3, v3, 16384, (int)QKV1);
        k_attn7<<<dim3(2, 32, 12), 512, 0, stream>>>(q3, k3, v3, TM, att, (int)QKV1, 0);
        k_oproj_cvt<<<dim3(32, 8), 256, 0, stream>>>(att, Wo, X, gamma, beta, out);
    } else {
        unsigned short* q_ws   = (unsigned short*)(ws);
        unsigned short* k_ws   = (unsigned short*)(ws + QKV1B);
        unsigned short* v_ws   = (unsigned short*)(ws + 2 * QKV1B);
        unsigned short* att_ws = (unsigned short*)(ws + 3 * QKV1B);
        const int tsel[3] = {0, 1, 3};
        for (int t = 0; t < 3; ++t) {
            k_qkv_cvt<<<dim3(32, 4, 1), 256, 0, stream>>>(
                X, Wq + (size_t)t * 16384, Wk + (size_t)t * 16384, Wv + (size_t)t * 16384,
                q_ws, k_ws, v_ws, 0, 0);
            k_attn7<<<dim3(2, 32, 4), 512, 0, stream>>>(
                q_ws, k_ws, v_ws, TM + (size_t)tsel[t] * 262144, att_ws, 0, t * 128);
        }
        k_oproj_cvt<<<dim3(32, 8), 256, 0, stream>>>(att_ws, Wo, X, gamma, beta, out);
    }
}

// Round 10
// 165.881 us; speedup vs baseline: 1.1903x; 1.0086x over previous
//
#include <hip/hip_runtime.h>

// ---------------- problem constants ----------------
// B*P=32, N=512, D=128, H=4, DK=32, T=3 (tm {0,1,3}; tsel(t)=t+(t>>1))
// Inputs f32, OUTPUT f32. XL path (ws >= 54.9MB) confirmed.
// R23 = FINAL: byte-exact revert to R16, the measured-best configuration
//   (165.4us total; k_attn4 51.4us).
// Search ledger (10 rounds):
//   WIN : tm depth-1 prefetch in k_attn (R16, -6us).
//   RETIRED: S^T orientation (R14/R17/R19: 77-81us clean; P-store bank
//     serialization + 16-line tm gathers beat the VALU savings);
//     kf prefetch (+2us, occ drop), ceil-fma (neutral), split-Ps dual-strip
//     pipeline (R22: +2.3us; shared-Ps serialization wasn't binding),
//     forced min-waves occupancy (R17: 420MB scratch spill),
//     launch fusion (R20 confounded / R21 clean-negative),
//     non-attn restructures (R15: -1.1us; budget immovable).
// Plateau diagnosis: k_attn4 is latency-bound (~50% issue-idle, MfmaUtil 9,
//   VALUBusy 39, HBM 12%); every identified latency source is hidden, proven
//   non-binding, or structural. Non-attn ~113us is 3x-confirmed insensitive.

typedef __attribute__((ext_vector_type(8))) short  short8;
typedef __attribute__((ext_vector_type(4))) float  floatx4;

#define WS_BIG   50331648ull                  // q3/k3/v3 (37.7MB) + att (12.6MB)
#define WS_XL    54919168ull                  // + Xb 4MB + Wb 288KB + Wob 96KB
#define QSCALE   0.25503486f                  // (1/sqrt(32)) * log2(e)

__device__ __forceinline__ unsigned short f2b(float f) {
    union { float f; unsigned int i; } v; v.f = f;
    unsigned int x = v.i;
    return (unsigned short)((x + 0x7fffu + ((x >> 16) & 1u)) >> 16);
}
__device__ __forceinline__ unsigned int fbits(float f) {
    union { float f; unsigned int i; } v; v.f = f; return v.i;
}
__device__ __forceinline__ short8 cvt8(const float* p) {
    floatx4 a = *(const floatx4*)p;
    floatx4 b = *(const floatx4*)(p + 4);
    short8 r;
    r[0] = (short)f2b(a[0]); r[1] = (short)f2b(a[1]);
    r[2] = (short)f2b(a[2]); r[3] = (short)f2b(a[3]);
    r[4] = (short)f2b(b[0]); r[5] = (short)f2b(b[1]);
    r[6] = (short)f2b(b[2]); r[7] = (short)f2b(b[3]);
    return r;
}

// ---------------- K0: one-time f32->bf16 conversion of X, Wq/Wk/Wv, Wo --------
__global__ __launch_bounds__(256) void k_prep(
    const float* __restrict__ X,  const float* __restrict__ Wq,
    const float* __restrict__ Wk, const float* __restrict__ Wv,
    const float* __restrict__ Wo,
    unsigned short* __restrict__ Xb, unsigned short* __restrict__ Wb,
    unsigned short* __restrict__ Wob)
{
    size_t i = ((size_t)blockIdx.x * 256 + threadIdx.x) * 8;
    const float* src; unsigned short* dst; size_t off;
    if      (i < 2097152) { src = X;  dst = Xb;          off = i; }
    else if (i < 2146304) { src = Wq; dst = Wb;          off = i - 2097152; }
    else if (i < 2195456) { src = Wk; dst = Wb + 49152;  off = i - 2146304; }
    else if (i < 2244608) { src = Wv; dst = Wb + 98304;  off = i - 2195456; }
    else                  { src = Wo; dst = Wob;         off = i - 2244608; }
    *(short8*)&dst[off] = cvt8(&src[off]);
}

// ---------------- K1a: QKV projection, one (qkv,t) per block (R15-proven) -----
__global__ __launch_bounds__(256) void k_qkv_pre2(
    const unsigned short* __restrict__ Xb,   // [32][512][128] bf16
    const unsigned short* __restrict__ Wb,   // [3 qkv][3 t][128][128] bf16
    unsigned short* __restrict__ q_ws,
    unsigned short* __restrict__ k_ws,
    unsigned short* __restrict__ v_ws)
{
    int bp = blockIdx.x, mt = blockIdx.y, z = blockIdx.z;
    int qkv = z / 3, t = z % 3;
    __shared__ unsigned short Xs[128 * 128];     // 32 KB
    __shared__ unsigned short Cs[4][32 * 128];   // 32 KB (8KB per wave)
    int tid = threadIdx.x;
    int lane = tid & 63, wv = tid >> 6;
    int l15 = lane & 15, quad = lane >> 4;

    const unsigned short* Xbase = Xb + ((size_t)bp * 512 + mt * 128) * 128;
    for (int i = 0; i < 8; ++i) {
        int e = (i * 256 + tid) * 8;
        *(short8*)&Xs[e] = *(const short8*)&Xbase[e];
    }
    __syncthreads();

    unsigned short* Osel[3] = { q_ws, k_ws, v_ws };
    int rt0 = wv * 2, rt1 = wv * 2 + 1;

    const unsigned short* Wt = Wb + qkv * 49152 + t * 16384;
    unsigned short* Ob = Osel[qkv] + (size_t)t * 2097152
                       + ((size_t)bp * 512 + mt * 128 + wv * 32) * 128;
    float sc = (qkv == 0) ? QSCALE : 1.0f;

    for (int ct = 0; ct < 8; ++ct) {
        short8 bfr[4];
        for (int kk = 0; kk < 4; ++kk)
            bfr[kk] = *(const short8*)&Wt[(size_t)(ct * 16 + l15) * 128 + kk * 32 + quad * 8];
        floatx4 acc0 = {0.f, 0.f, 0.f, 0.f};
        floatx4 acc1 = {0.f, 0.f, 0.f, 0.f};
        for (int kk = 0; kk < 4; ++kk) {
            short8 a0 = *(const short8*)&Xs[(rt0 * 16 + l15) * 128 + kk * 32 + quad * 8];
            short8 a1 = *(const short8*)&Xs[(rt1 * 16 + l15) * 128 + kk * 32 + quad * 8];
            acc0 = __builtin_amdgcn_mfma_f32_16x16x32_bf16(a0, bfr[kk], acc0, 0, 0, 0);
            acc1 = __builtin_amdgcn_mfma_f32_16x16x32_bf16(a1, bfr[kk], acc1, 0, 0, 0);
        }
        #pragma unroll
        for (int i = 0; i < 4; ++i) {
            int row = quad * 4 + i;
            int swz = (row & 7) << 4;
            int col = (ct * 16 + l15) ^ swz;
            Cs[wv][row * 128 + col]        = f2b(acc0[i] * sc);
            Cs[wv][(16 + row) * 128 + col] = f2b(acc1[i] * sc);
        }
    }
    #pragma unroll
    for (int j = 0; j < 8; ++j) {
        int flat = j * 64 + lane;
        int r = flat >> 4;
        int cg = (flat & 15) * 8;
        int cgs = cg ^ ((r & 7) << 4);
        *(short8*)&Ob[(size_t)r * 128 + cg] = *(const short8*)&Cs[wv][r * 128 + cgs];
    }
}

// ---------------- K1b: QKV projection, inline-cvt fallback --------------------
__global__ __launch_bounds__(256) void k_qkv_cvt(
    const float* __restrict__ X,
    const float* __restrict__ Wq, const float* __restrict__ Wk,
    const float* __restrict__ Wv,
    unsigned short* __restrict__ q_ws, unsigned short* __restrict__ k_ws,
    unsigned short* __restrict__ v_ws,
    int wstride, int ostride)
{
    int bp = blockIdx.x, mt = blockIdx.y, tz = blockIdx.z;
    __shared__ unsigned short Xs[128 * 128];
    int tid = threadIdx.x;
    int lane = tid & 63, wv = tid >> 6;
    int l15 = lane & 15, quad = lane >> 4;

    const float* Xbase = X + ((size_t)bp * 512 + mt * 128) * 128;
    for (int i = 0; i < 8; ++i) {
        int e = (i * 256 + tid) * 8;
        *(short8*)&Xs[e] = cvt8(&Xbase[e]);
    }
    __syncthreads();

    size_t woff = (size_t)tz * wstride;
    size_t ooff = (size_t)tz * ostride;
    const float* Wsel[3] = { Wq + woff, Wk + woff, Wv + woff };
    unsigned short* Osel[3] = { q_ws + ooff, k_ws + ooff, v_ws + ooff };

    for (int qkv = 0; qkv < 3; ++qkv) {
        const float* Wt = Wsel[qkv];
        unsigned short* Ob = Osel[qkv] + ((size_t)bp * 512 + mt * 128) * 128;
        float sc = (qkv == 0) ? QSCALE : 1.0f;
        for (int ct = 0; ct < 8; ++ct) {
            short8 bfr[4];
            for (int kk = 0; kk < 4; ++kk)
                bfr[kk] = cvt8(&Wt[(size_t)(ct * 16 + l15) * 128 + kk * 32 + quad * 8]);
            floatx4 acc0 = {0.f, 0.f, 0.f, 0.f};
            floatx4 acc1 = {0.f, 0.f, 0.f, 0.f};
            int rt0 = wv * 2, rt1 = wv * 2 + 1;
            for (int kk = 0; kk < 4; ++kk) {
                short8 a0 = *(const short8*)&Xs[(rt0 * 16 + l15) * 128 + kk * 32 + quad * 8];
                short8 a1 = *(const short8*)&Xs[(rt1 * 16 + l15) * 128 + kk * 32 + quad * 8];
                acc0 = __builtin_amdgcn_mfma_f32_16x16x32_bf16(a0, bfr[kk], acc0, 0, 0, 0);
                acc1 = __builtin_amdgcn_mfma_f32_16x16x32_bf16(a1, bfr[kk], acc1, 0, 0, 0);
            }
            int col = ct * 16 + l15;
            for (int i = 0; i < 4; ++i) {
                Ob[(size_t)(rt0 * 16 + quad * 4 + i) * 128 + col] = f2b(acc0[i] * sc);
                Ob[(size_t)(rt1 * 16 + quad * 4 + i) * 128 + col] = f2b(acc1[i] * sc);
            }
        }
    }
}

// ---------------- K2: dense MFMA attention + depth-1 tm pipeline (R16 exact) --
// grid (nc2=2, bp=32, z=t*4+h) = 768 blocks = 3/CU (52KB LDS). Proven 51.4us:
// VGPR 56, MfmaUtil ~9, VALUBusy ~39, conflicts 786K. tm loads for body (c,s)
// issued one body earlier into rotating sets tmA/tmB; rolling base tpc (+64/c).
__global__ __launch_bounds__(512) void k_attn4(
    const unsigned short* __restrict__ q_ws,   // bf16, pre-scaled by QSCALE
    const unsigned short* __restrict__ k_ws,
    const unsigned short* __restrict__ v_ws,
    const float* __restrict__ tm,
    unsigned short* __restrict__ att_ws,       // [32][512][384] bf16
    int qkv_stride, int toff0)
{
    int nc2 = blockIdx.x;
    int bp = blockIdx.y;
    int z  = blockIdx.z;
    int t = z >> 2, h = z & 3;
    size_t qoff = (size_t)t * (size_t)qkv_stride;
    const float* tmt = tm + (size_t)(t + (t >> 1)) * 262144;
    int toff = toff0 + t * 128;

    __shared__ unsigned short Vt[32][516];
    __shared__ unsigned short Ps[8][16][72];

    int tid = threadIdx.x, lane = tid & 63, wv = tid >> 6;
    int l15 = lane & 15, quad = lane >> 4;

    {
        const unsigned short* vp = v_ws + qoff + ((size_t)bp * 512 + tid) * 128 + h * 32;
        short8 a = *(const short8*)vp;
        short8 b = *(const short8*)(vp + 8);
        short8 c = *(const short8*)(vp + 16);
        short8 d = *(const short8*)(vp + 24);
        #pragma unroll
        for (int j = 0; j < 8; ++j) {
            Vt[j][tid]      = (unsigned short)a[j];
            Vt[8 + j][tid]  = (unsigned short)b[j];
            Vt[16 + j][tid] = (unsigned short)c[j];
            Vt[24 + j][tid] = (unsigned short)d[j];
        }
    }
    int n0 = nc2 * 256 + wv * 16;              // strip 0; strip 1 at n0+128
    short8 qf[2];
    qf[0] = *(const short8*)&q_ws[qoff +
        ((size_t)bp * 512 + n0 + l15) * 128 + h * 32 + quad * 8];
    qf[1] = *(const short8*)&q_ws[qoff +
        ((size_t)bp * 512 + n0 + 128 + l15) * 128 + h * 32 + quad * 8];
    __syncthreads();

    const unsigned short* Kb = k_ws + qoff + (size_t)bp * 512 * 128 + h * 32;
    // per-lane tm base: row (n0 + s*128 + quad*4 + i), col (mb + ti*16 + l15)
    const float* tpc = tmt + (size_t)(n0 + quad * 4) * 512 + l15;

    floatx4 O0[2] = {{0.f,0.f,0.f,0.f},{0.f,0.f,0.f,0.f}};
    floatx4 O1[2] = {{0.f,0.f,0.f,0.f},{0.f,0.f,0.f,0.f}};
    float za[2][4] = {{0.f,0.f,0.f,0.f},{0.f,0.f,0.f,0.f}};
    const floatx4 zero4 = {0.f, 0.f, 0.f, 0.f};

    float tmA[16], tmB[16];                    // [ti*4+i], rotating sets
    #pragma unroll
    for (int ti = 0; ti < 4; ++ti)
        #pragma unroll
        for (int i = 0; i < 4; ++i)
            tmA[ti * 4 + i] = tpc[i * 512 + ti * 16];   // (c=0, s=0)

    for (int c = 0; c < 8; ++c) {
        int mb = c * 64;
        short8 kf0 = *(const short8*)&Kb[(size_t)(mb +  0 + l15) * 128 + quad * 8];
        short8 kf1 = *(const short8*)&Kb[(size_t)(mb + 16 + l15) * 128 + quad * 8];
        short8 kf2 = *(const short8*)&Kb[(size_t)(mb + 32 + l15) * 128 + quad * 8];
        short8 kf3 = *(const short8*)&Kb[(size_t)(mb + 48 + l15) * 128 + quad * 8];

        // ================= s = 0 : prefetch (c, s=1) into tmB =================
        #pragma unroll
        for (int ti = 0; ti < 4; ++ti)
            #pragma unroll
            for (int i = 0; i < 4; ++i)
                tmB[ti * 4 + i] = tpc[(128 + i) * 512 + ti * 16];
        {
            floatx4 S[4];
            S[0] = __builtin_amdgcn_mfma_f32_16x16x32_bf16(qf[0], kf0, zero4, 0, 0, 0);
            S[1] = __builtin_amdgcn_mfma_f32_16x16x32_bf16(qf[0], kf1, zero4, 0, 0, 0);
            S[2] = __builtin_amdgcn_mfma_f32_16x16x32_bf16(qf[0], kf2, zero4, 0, 0, 0);
            S[3] = __builtin_amdgcn_mfma_f32_16x16x32_bf16(qf[0], kf3, zero4, 0, 0, 0);
            #pragma unroll
            for (int ti = 0; ti < 4; ++ti) {
                #pragma unroll
                for (int i = 0; i < 4; ++i) {
                    float tmv = tmA[ti * 4 + i];
                    float e = __builtin_amdgcn_exp2f(S[ti][i]);
                    za[0][i] += (tmv != 0.0f) ? e : 0.0f;
                    float w = e * tmv;                    // ==0 when masked
                    Ps[wv][quad * 4 + i][ti * 16 + l15] =
                        (unsigned short)((fbits(w) + 0x8000u) >> 16);  // half-up
                }
            }
            #pragma unroll
            for (int kc = 0; kc < 2; ++kc) {
                short8 pa  = *(const short8*)&Ps[wv][l15][kc * 32 + quad * 8];
                short8 vb0 = *(const short8*)&Vt[l15][mb + kc * 32 + quad * 8];
                short8 vb1 = *(const short8*)&Vt[16 + l15][mb + kc * 32 + quad * 8];
                O0[0] = __builtin_amdgcn_mfma_f32_16x16x32_bf16(pa, vb0, O0[0], 0, 0, 0);
                O1[0] = __builtin_amdgcn_mfma_f32_16x16x32_bf16(pa, vb1, O1[0], 0, 0, 0);
            }
        }

        // ================= s = 1 : prefetch (c+1, s=0) into tmA ===============
        #pragma unroll
        for (int ti = 0; ti < 4; ++ti)
            #pragma unroll
            for (int i = 0; i < 4; ++i)
                tmA[ti * 4 + i] = tpc[i * 512 + 64 + ti * 16];
        {
            floatx4 S[4];
            S[0] = __builtin_amdgcn_mfma_f32_16x16x32_bf16(qf[1], kf0, zero4, 0, 0, 0);
            S[1] = __builtin_amdgcn_mfma_f32_16x16x32_bf16(qf[1], kf1, zero4, 0, 0, 0);
            S[2] = __builtin_amdgcn_mfma_f32_16x16x32_bf16(qf[1], kf2, zero4, 0, 0, 0);
            S[3] = __builtin_amdgcn_mfma_f32_16x16x32_bf16(qf[1], kf3, zero4, 0, 0, 0);
            #pragma unroll
            for (int ti = 0; ti < 4; ++ti) {
                #pragma unroll
                for (int i = 0; i < 4; ++i) {
                    float tmv = tmB[ti * 4 + i];
                    float e = __builtin_amdgcn_exp2f(S[ti][i]);
                    za[1][i] += (tmv != 0.0f) ? e : 0.0f;
                    float w = e * tmv;
                    Ps[wv][quad * 4 + i][ti * 16 + l15] =
                        (unsigned short)((fbits(w) + 0x8000u) >> 16);
                }
            }
            #pragma unroll
            for (int kc = 0; kc < 2; ++kc) {
                short8 pa  = *(const short8*)&Ps[wv][l15][kc * 32 + quad * 8];
                short8 vb0 = *(const short8*)&Vt[l15][mb + kc * 32 + quad * 8];
                short8 vb1 = *(const short8*)&Vt[16 + l15][mb + kc * 32 + quad * 8];
                O0[1] = __builtin_amdgcn_mfma_f32_16x16x32_bf16(pa, vb0, O0[1], 0, 0, 0);
                O1[1] = __builtin_amdgcn_mfma_f32_16x16x32_bf16(pa, vb1, O1[1], 0, 0, 0);
            }
        }
        tpc += 64;
    }

    #pragma unroll
    for (int s = 0; s < 2; ++s) {
        #pragma unroll
        for (int d = 1; d < 16; d <<= 1) {
            #pragma unroll
            for (int i = 0; i < 4; ++i) za[s][i] += __shfl_xor(za[s][i], d, 64);
        }
        #pragma unroll
        for (int i = 0; i < 4; ++i) {
            float rz = 1.0f / za[s][i];
            size_t row = (size_t)bp * 512 + n0 + s * 128 + quad * 4 + i;
            att_ws[row * 384 + toff + h * 32 + l15]      = f2b(O0[s][i] * rz);
            att_ws[row * 384 + toff + h * 32 + 16 + l15] = f2b(O1[s][i] * rz);
        }
    }
}

// ---------------- K3a: out-projection, 32-row blocks + ct-split waves ---------
__global__ __launch_bounds__(256) void k_oproj_pre2(
    const unsigned short* __restrict__ att_ws,   // [32][512][384] bf16
    const unsigned short* __restrict__ Wob,      // [128][384] bf16
    const float* __restrict__ X,
    const float* __restrict__ gamma,
    const float* __restrict__ beta,
    float* __restrict__ out)
{
    int bp = blockIdx.x;
    int mt = blockIdx.y;                         // 16 tiles of 32 rows
    __shared__ unsigned short As[32 * 128];      // 8 KB
    __shared__ unsigned short Ws[128 * 128];     // 32 KB
    __shared__ float Ls_s[2][32];                // per-ct-half row partials
    __shared__ float Ls_q[2][32];
    int tid = threadIdx.x, lane = tid & 63, wv = tid >> 6;
    int l15 = lane & 15, quad = lane >> 4;
    int rtile = wv & 1, chalf = wv >> 1;

    floatx4 acc[4];
    for (int ct = 0; ct < 4; ++ct) acc[ct] = (floatx4){0.f, 0.f, 0.f, 0.f};
    size_t rowbase = (size_t)bp * 512 + mt * 32;

    for (int kc = 0; kc < 3; ++kc) {
        __syncthreads();
        for (int i = 0; i < 2; ++i) {
            int flat = i * 256 + tid;
            int row = flat >> 4, colg = (flat & 15) * 8;
            *(short8*)&As[row * 128 + colg] =
                *(const short8*)&att_ws[(rowbase + row) * 384 + kc * 128 + colg];
        }
        for (int i = 0; i < 8; ++i) {
            int flat = i * 256 + tid;
            int row = flat >> 4, colg = (flat & 15) * 8;
            *(short8*)&Ws[row * 128 + colg] =
                *(const short8*)&Wob[(size_t)row * 384 + kc * 128 + colg];
        }
        __syncthreads();
        for (int ct = 0; ct < 4; ++ct) {
            for (int kk = 0; kk < 4; ++kk) {
                short8 a = *(const short8*)&As[(rtile * 16 + l15) * 128 + kk * 32 + quad * 8];
                short8 b = *(const short8*)&Ws[((chalf * 4 + ct) * 16 + l15) * 128 + kk * 32 + quad * 8];
                acc[ct] = __builtin_amdgcn_mfma_f32_16x16x32_bf16(a, b, acc[ct], 0, 0, 0);
            }
        }
    }

    float vals[4][4];                            // [i][ct], static indexing
    #pragma unroll
    for (int i = 0; i < 4; ++i) {
        int lrow = rtile * 16 + quad * 4 + i;
        size_t grow = rowbase + lrow;
        float s = 0.f, sq = 0.f;
        #pragma unroll
        for (int ct = 0; ct < 4; ++ct) {
            int col = (chalf * 4 + ct) * 16 + l15;
            float v = acc[ct][i] + X[grow * 128 + col];
            vals[i][ct] = v;
            s += v; sq += v * v;
        }
        #pragma unroll
        for (int d = 1; d < 16; d <<= 1) {
            s  += __shfl_xor(s, d, 64);
            sq += __shfl_xor(sq, d, 64);
        }
        if (l15 == 0) { Ls_s[chalf][lrow] = s; Ls_q[chalf][lrow] = sq; }
    }
    __syncthreads();
    #pragma unroll
    for (int i = 0; i < 4; ++i) {
        int lrow = rtile * 16 + quad * 4 + i;
        size_t grow = rowbase + lrow;
        float st  = Ls_s[0][lrow] + Ls_s[1][lrow];
        float sqt = Ls_q[0][lrow] + Ls_q[1][lrow];
        float mu = st * (1.0f / 128.0f);
        float var = sqt * (1.0f / 128.0f) - mu * mu;
        float rs = rsqrtf(var + 1e-5f);
        #pragma unroll
        for (int ct = 0; ct < 4; ++ct) {
            int col = (chalf * 4 + ct) * 16 + l15;
            out[grow * 128 + col] = (vals[i][ct] - mu) * rs * gamma[col] + beta[col];
        }
    }
}

// ---------------- K3b: out-projection, inline-cvt fallback --------------------
__global__ __launch_bounds__(256) void k_oproj_cvt(
    const unsigned short* __restrict__ att_ws,
    const float* __restrict__ Wo,
    const float* __restrict__ X,
    const float* __restrict__ gamma,
    const float* __restrict__ beta,
    float* __restrict__ out)
{
    int bp = blockIdx.x;
    int mt = blockIdx.y;
    __shared__ unsigned short As[64 * 128];
    __shared__ unsigned short Ws[128 * 128];
    int tid = threadIdx.x, lane = tid & 63, wv = tid >> 6;
    int l15 = lane & 15, quad = lane >> 4;

    floatx4 acc[8];
    for (int ct = 0; ct < 8; ++ct) acc[ct] = (floatx4){0.f, 0.f, 0.f, 0.f};
    size_t rowbase = (size_t)bp * 512 + mt * 64;

    for (int kc = 0; kc < 3; ++kc) {
        __syncthreads();
        for (int i = 0; i < 4; ++i) {
            int flat = i * 256 + tid;
            int row = flat >> 4, colg = (flat & 15) * 8;
            *(short8*)&As[row * 128 + colg] =
                *(const short8*)&att_ws[(rowbase + row) * 384 + kc * 128 + colg];
        }
        for (int i = 0; i < 8; ++i) {
            int flat = i * 256 + tid;
            int row = flat >> 4, colg = (flat & 15) * 8;
            *(short8*)&Ws[row * 128 + colg] = cvt8(&Wo[(size_t)row * 384 + kc * 128 + colg]);
        }
        __syncthreads();
        for (int ct = 0; ct < 8; ++ct) {
            for (int kk = 0; kk < 4; ++kk) {
                short8 a = *(const short8*)&As[(wv * 16 + l15) * 128 + kk * 32 + quad * 8];
                short8 b = *(const short8*)&Ws[(ct * 16 + l15) * 128 + kk * 32 + quad * 8];
                acc[ct] = __builtin_amdgcn_mfma_f32_16x16x32_bf16(a, b, acc[ct], 0, 0, 0);
            }
        }
    }

    for (int i = 0; i < 4; ++i) {
        int lrow = wv * 16 + quad * 4 + i;
        size_t grow = rowbase + lrow;
        float vals[8];
        float s = 0.f, sq = 0.f;
        for (int ct = 0; ct < 8; ++ct) {
            int col = ct * 16 + l15;
            float v = acc[ct][i] + X[grow * 128 + col];
            vals[ct] = v;
            s += v; sq += v * v;
        }
        for (int d = 1; d < 16; d <<= 1) {
            s  += __shfl_xor(s, d, 64);
            sq += __shfl_xor(sq, d, 64);
        }
        float mu = s * (1.0f / 128.0f);
        float var = sq * (1.0f / 128.0f) - mu * mu;
        float rs = rsqrtf(var + 1e-5f);
        for (int ct = 0; ct < 8; ++ct) {
            int col = ct * 16 + l15;
            out[grow * 128 + col] = (vals[ct] - mu) * rs * gamma[col] + beta[col];
        }
    }
}

// ---------------- launcher ----------------
extern "C" void kernel_launch(void* const* d_in, const int* in_sizes, int n_in,
                              void* d_out, int out_size, void* d_ws, size_t ws_size,
                              hipStream_t stream) {
    const float* X     = (const float*)d_in[0];
    const float* TM    = (const float*)d_in[2];
    const float* Wq    = (const float*)d_in[3];
    const float* Wk    = (const float*)d_in[4];
    const float* Wv    = (const float*)d_in[5];
    const float* Wo    = (const float*)d_in[6];
    const float* gamma = (const float*)d_in[7];
    const float* beta  = (const float*)d_in[8];
    float* out = (float*)d_out;

    char* ws = (char*)d_ws;
    const size_t QKV1 = 2097152;             // elems per t per tensor
    const size_t QKV1B = QKV1 * 2;           // 4 MB

    if (ws_size >= WS_XL) {
        unsigned short* q3  = (unsigned short*)(ws);
        unsigned short* k3  = (unsigned short*)(ws + 3 * QKV1B);
        unsigned short* v3  = (unsigned short*)(ws + 6 * QKV1B);
        unsigned short* att = (unsigned short*)(ws + 9 * QKV1B);
        unsigned short* Xb  = (unsigned short*)(ws + 50331648ull);
        unsigned short* Wb  = (unsigned short*)(ws + 54525952ull);
        unsigned short* Wob = (unsigned short*)(ws + 54820864ull);
        k_prep<<<dim3(1120), 256, 0, stream>>>(X, Wq, Wk, Wv, Wo, Xb, Wb, Wob);
        k_qkv_pre2<<<dim3(32, 4, 9), 256, 0, stream>>>(Xb, Wb, q3, k3, v3);
        k_attn4<<<dim3(2, 32, 12), 512, 0, stream>>>(q3, k3, v3, TM, att, (int)QKV1, 0);
        k_oproj_pre2<<<dim3(32, 16), 256, 0, stream>>>(att, Wob, X, gamma, beta, out);
    } else if (ws_size >= WS_BIG) {
        unsigned short* q3  = (unsigned short*)(ws);
        unsigned short* k3  = (unsigned short*)(ws + 3 * QKV1B);
        unsigned short* v3  = (unsigned short*)(ws + 6 * QKV1B);
        unsigned short* att = (unsigned short*)(ws + 9 * QKV1B);
        k_qkv_cvt<<<dim3(32, 4, 3), 256, 0, stream>>>(
            X, Wq, Wk, Wv, q3, k3, v3, 16384, (int)QKV1);
        k_attn4<<<dim3(2, 32, 12), 512, 0, stream>>>(q3, k3, v3, TM, att, (int)QKV1, 0);
        k_oproj_cvt<<<dim3(32, 8), 256, 0, stream>>>(att, Wo, X, gamma, beta, out);
    } else {
        unsigned short* q_ws   = (unsigned short*)(ws);
        unsigned short* k_ws   = (unsigned short*)(ws + QKV1B);
        unsigned short* v_ws   = (unsigned short*)(ws + 2 * QKV1B);
        unsigned short* att_ws = (unsigned short*)(ws + 3 * QKV1B);
        const int tsel[3] = {0, 1, 3};
        for (int t = 0; t < 3; ++t) {
            k_qkv_cvt<<<dim3(32, 4, 1), 256, 0, stream>>>(
                X, Wq + (size_t)t * 16384, Wk + (size_t)t * 16384, Wv + (size_t)t * 16384,
                q_ws, k_ws, v_ws, 0, 0);
            k_attn4<<<dim3(2, 32, 4), 512, 0, stream>>>(
                q_ws, k_ws, v_ws, TM + (size_t)tsel[t] * 262144, att_ws, 0, t * 128);
        }
        k_oproj_cvt<<<dim3(32, 8), 256, 0, stream>>>(att_ws, Wo, X, gamma, beta, out);
    }
}